// Round 1
// baseline (23967.780 us; speedup 1.0000x reference)
//
#include <hip/hip_runtime.h>
#include <hip/hip_cooperative_groups.h>

namespace cg = cooperative_groups;

#define NB 64      // batch
#define NT 64      // time
#define ND 1024    // DETER
#define NH 1024    // HID
#define NE 1536    // EMBED
#define NA 6       // ACT
#define NSC 1024   // STOCH*CLASSES
#define GIN 1030   // GRU_IN
#define W1STR 2560 // post_w1 row stride (ND+NE)
#define EPS 1e-5f

// ---- workspace layout (float offsets) ----
#define O_EPRE   0u            // [T][NH][NB]  (reused as ph1 by prior pass)
#define O_HHIST  4194304u      // [T][ND][NB]
#define O_LHIST  8388608u      // [T][NSC][NB] (post logits, [t][j][b])
#define O_EMBT   4194304u      // overlay on HHIST+LHIST pre-scan: [T][NE][NB]
#define O_HKPP   12582912u     // [2][ND][NB] kept-h ping-pong
#define O_PHT    12713984u     // [NH][NB]
#define O_PS1    12779520u     // [256][NB] partial LN sums
#define O_PS2    12795904u     // [256][NB] partial LN sumsq
#define O_GMAX   12812288u     // u64[32][NB] packed argmax
#define O_ZIDX   12816384u     // int[T][32][NB]
#define O_ACTT   12947456u     // [T][NA][NB]
#define O_KEEPT  12972032u     // [T][NB]
#define O_PSTAT  12976128u     // [T][NB][2] prior LN stats
// end: 12984320 floats = ~49.5 MB

// out layout (floats)
#define OUT_LATENT 0u
#define OUT_HSEQ   8388608u
#define OUT_POST   12582912u
#define OUT_PRIOR  16777216u

// =================== K0: transposes + zero-init ===================
__global__ void k0_prep(const float* __restrict__ embeds,
                        const float* __restrict__ actions,
                        const int* __restrict__ isfirst,
                        float* __restrict__ ws)
{
    int blk = blockIdx.x, tid = threadIdx.x;
    int rr = tid >> 6, ln = tid & 63;
    if (blk < 1536) {
        // embeds (B,T,E) -> emb_T [t][e][b]
        int t = blk / 24, et = blk % 24, e0 = et * 64;
        __shared__ float tile[64][65];
        for (int q = 0; q < 16; ++q) {
            int b = q * 4 + rr;
            tile[b][ln] = embeds[((size_t)b * NT + t) * NE + e0 + ln];
        }
        __syncthreads();
        float* embT = ws + O_EMBT + (size_t)t * NE * NB;
        for (int q = 0; q < 16; ++q) {
            int e = q * 4 + rr;
            embT[(size_t)(e0 + e) * NB + ln] = tile[ln][e];
        }
    } else if (blk == 1536) {
        for (int i = tid; i < NT * NA * NB; i += 256) {
            int t = i / (NA * NB); int rem = i % (NA * NB);
            int a = rem / NB; int b = rem % NB;
            ws[O_ACTT + i] = actions[((size_t)b * NT + t) * NA + a];
        }
        for (int i = tid; i < NT * NB; i += 256) {
            int t = i / NB, b = i % NB;
            ws[O_KEEPT + i] = 1.f - (float)isfirst[(size_t)b * NT + t];
        }
    } else {
        for (int i = tid; i < ND * NB; i += 256) ws[O_HKPP + i] = 0.f;
        for (int i = tid; i < NT * NB * 2; i += 256) ws[O_PSTAT + i] = 0.f;
    }
}

// =================== K1: E_pre = emb @ post_w1[:,1024:]^T ===================
__global__ __launch_bounds__(256) void k1_epre(const float* __restrict__ qw1,
                                               float* __restrict__ ws)
{
    int blk = blockIdx.x;
    int t = blk >> 6, kg = blk & 63, k0 = kg * 16;
    int tid = threadIdx.x, w = tid >> 6, lane = tid & 63;
    const float* embT = ws + O_EMBT + (size_t)t * NE * NB;
    float acc[16];
#pragma unroll
    for (int i = 0; i < 16; ++i) acc[i] = 0.f;
    int e0 = w * 384;
    for (int e = e0; e < e0 + 384; ++e) {
        float ev = embT[(size_t)e * NB + lane];
#pragma unroll
        for (int kk = 0; kk < 16; ++kk)
            acc[kk] = fmaf(qw1[(size_t)(k0 + kk) * W1STR + ND + e], ev, acc[kk]);
    }
    __shared__ float red[4][16][64];
#pragma unroll
    for (int kk = 0; kk < 16; ++kk) red[w][kk][lane] = acc[kk];
    __syncthreads();
    float* epre = ws + O_EPRE + (size_t)t * NH * NB;
    for (int q = 0; q < 4; ++q) {
        int slot = tid + q * 256;
        int kk = slot >> 6, b = slot & 63;
        float v = red[0][kk][b] + red[1][kk][b] + red[2][kk][b] + red[3][kk][b];
        epre[(size_t)(k0 + kk) * NB + b] = v;
    }
}

// =================== K2: the cooperative scan ===================
__global__ __launch_bounds__(256, 1)
void k2_scan(const float* __restrict__ Wih, const float* __restrict__ Whh,
             const float* __restrict__ bih, const float* __restrict__ bhh,
             const float* __restrict__ qw1, const float* __restrict__ qb1,
             const float* __restrict__ qg,  const float* __restrict__ qbe,
             const float* __restrict__ qw2, const float* __restrict__ qb2,
             float* __restrict__ ws)
{
    cg::grid_group grid = cg::this_grid();
    const int blk = blockIdx.x, tid = threadIdx.x;
    const int w = tid >> 6, lane = tid & 63;

    float* hk_pp = ws + O_HKPP;
    float* hhist = ws + O_HHIST;
    float* lhist = ws + O_LHIST;
    float* epre  = ws + O_EPRE;
    float* phT   = ws + O_PHT;
    float* ps1   = ws + O_PS1;
    float* ps2   = ws + O_PS2;
    unsigned long long* gmax = (unsigned long long*)(ws + O_GMAX);
    int* zidx = (int*)(ws + O_ZIDX);
    const float* actT  = ws + O_ACTT;
    const float* keepT = ws + O_KEEPT;

    __shared__ float redA[4][12][64];
    __shared__ float redB[4][4][64];
    __shared__ float vst[4][64];
    __shared__ float sred1[4][64], sred2[4][64];
    __shared__ float smean[64], srstd[64];
    __shared__ unsigned long long pkst[4][64];

    const int d0 = blk * 4;  // owned dims (A) / hid dims (B) / logit dims (C)

    for (int t = 0; t < NT; ++t) {
        // ---------------- PHASE A: GRU -> h_new ----------------
        {
            const float* hk = hk_pp + (size_t)(t & 1) * ND * NB;
            float ar[4] = {0,0,0,0}, az[4] = {0,0,0,0}, an[4] = {0,0,0,0};
            int kk0 = w * 256;
            for (int k = kk0; k < kk0 + 256; ++k) {
                float hv = hk[(size_t)k * NB + lane];
#pragma unroll
                for (int dd = 0; dd < 4; ++dd) {
                    ar[dd] = fmaf(Whh[(size_t)(d0 + dd) * ND + k], hv, ar[dd]);
                    az[dd] = fmaf(Whh[(size_t)(1024 + d0 + dd) * ND + k], hv, az[dd]);
                    an[dd] = fmaf(Whh[(size_t)(2048 + d0 + dd) * ND + k], hv, an[dd]);
                }
            }
#pragma unroll
            for (int dd = 0; dd < 4; ++dd) {
                redA[w][dd][lane]     = ar[dd];
                redA[w][4 + dd][lane] = az[dd];
                redA[w][8 + dd][lane] = an[dd];
            }
            __syncthreads();
            {   // wave w finalizes dim d0+w for all b (=lane)
                int d = d0 + w;
                float ghr = redA[0][w][lane] + redA[1][w][lane] + redA[2][w][lane] + redA[3][w][lane] + bhh[d];
                float ghz = redA[0][4+w][lane] + redA[1][4+w][lane] + redA[2][4+w][lane] + redA[3][4+w][lane] + bhh[1024 + d];
                float ghn = redA[0][8+w][lane] + redA[1][8+w][lane] + redA[2][8+w][lane] + redA[3][8+w][lane] + bhh[2048 + d];
                float keep = keepT[t * NB + lane];
                float gxr = bih[d], gxz = bih[1024 + d], gxn = bih[2048 + d];
                if (t > 0) {
                    float sr = 0.f, sz = 0.f, sn = 0.f;
                    for (int g = 0; g < 32; ++g) {
                        unsigned long long pk = gmax[g * 64 + lane];
                        int c = 31 - (int)((unsigned)pk & 31u);
                        int col = g * 32 + c;
                        sr += Wih[(size_t)d * GIN + col];
                        sz += Wih[(size_t)(1024 + d) * GIN + col];
                        sn += Wih[(size_t)(2048 + d) * GIN + col];
                        if (blk == 0 && w == 0) zidx[(t - 1) * 32 * NB + g * NB + lane] = c;
                    }
                    gxr = fmaf(keep, sr, gxr);
                    gxz = fmaf(keep, sz, gxz);
                    gxn = fmaf(keep, sn, gxn);
                }
#pragma unroll
                for (int a = 0; a < NA; ++a) {
                    float av = actT[(t * NA + a) * NB + lane];
                    gxr = fmaf(Wih[(size_t)d * GIN + ND + a], av, gxr);
                    gxz = fmaf(Wih[(size_t)(1024 + d) * GIN + ND + a], av, gxz);
                    gxn = fmaf(Wih[(size_t)(2048 + d) * GIN + ND + a], av, gxn);
                }
                float r = 1.f / (1.f + expf(-(gxr + ghr)));
                float u = 1.f / (1.f + expf(-(gxz + ghz)));
                float n = tanhf(gxn + r * ghn);
                float hprev = hk[(size_t)d * NB + lane];   // already keep-masked
                float hnew = (1.f - u) * n + u * hprev;
                hhist[((size_t)t * ND + d) * NB + lane] = hnew;
                if (t < NT - 1)
                    hk_pp[(size_t)((t + 1) & 1) * ND * NB + (size_t)d * NB + lane]
                        = hnew * keepT[(t + 1) * NB + lane];
            }
        }
        grid.sync();  // S1
        // ---------------- PHASE B: post w1 (h part) + E_pre ----------------
        {
            const float* hrow = hhist + (size_t)t * ND * NB;
            float acc[4] = {0,0,0,0};
            int dd0 = w * 256;
            for (int d = dd0; d < dd0 + 256; ++d) {
                float hv = hrow[(size_t)d * NB + lane];
#pragma unroll
                for (int kk = 0; kk < 4; ++kk)
                    acc[kk] = fmaf(qw1[(size_t)(d0 + kk) * W1STR + d], hv, acc[kk]);
            }
#pragma unroll
            for (int kk = 0; kk < 4; ++kk) redB[w][kk][lane] = acc[kk];
            if (blk == 0) {  // reset argmax accumulators (visible to C after S2)
                for (int i = tid; i < 2048; i += 256) gmax[i] = 0ull;
            }
            __syncthreads();
            {
                int kk = tid >> 6, b = tid & 63;
                float v = redB[0][kk][b] + redB[1][kk][b] + redB[2][kk][b] + redB[3][kk][b];
                v += qb1[d0 + kk] + epre[((size_t)t * NH + d0 + kk) * NB + b];
                phT[(size_t)(d0 + kk) * NB + b] = v;
                vst[kk][b] = v;
            }
            __syncthreads();
            if (tid < 64) {
                float s1 = 0.f, s2 = 0.f;
#pragma unroll
                for (int kk = 0; kk < 4; ++kk) { float v = vst[kk][tid]; s1 += v; s2 = fmaf(v, v, s2); }
                ps1[blk * NB + tid] = s1;
                ps2[blk * NB + tid] = s2;
            }
        }
        grid.sync();  // S2
        // ---------------- PHASE C: LN+SiLU+post w2 + argmax ----------------
        {
            {
                float s1 = 0.f, s2 = 0.f;
                for (int bb = w * 64; bb < w * 64 + 64; ++bb) {
                    s1 += ps1[bb * NB + lane];
                    s2 += ps2[bb * NB + lane];
                }
                sred1[w][lane] = s1; sred2[w][lane] = s2;
            }
            __syncthreads();
            if (tid < 64) {
                float s1 = sred1[0][tid] + sred1[1][tid] + sred1[2][tid] + sred1[3][tid];
                float s2 = sred2[0][tid] + sred2[1][tid] + sred2[2][tid] + sred2[3][tid];
                float mean = s1 * (1.f / NH);
                float var = s2 * (1.f / NH) - mean * mean;
                smean[tid] = mean;
                srstd[tid] = 1.f / sqrtf(var + EPS);
            }
            __syncthreads();
            float mean = smean[lane], rstd = srstd[lane];
            float acc[4] = {0,0,0,0};
            int kk0 = w * 256;
            for (int k = kk0; k < kk0 + 256; ++k) {
                float v = phT[(size_t)k * NB + lane];
                float x = fmaf((v - mean) * rstd, qg[k], qbe[k]);
                float s = x / (1.f + expf(-x));
#pragma unroll
                for (int jj = 0; jj < 4; ++jj)
                    acc[jj] = fmaf(qw2[(size_t)(d0 + jj) * NH + k], s, acc[jj]);
            }
#pragma unroll
            for (int jj = 0; jj < 4; ++jj) redB[w][jj][lane] = acc[jj];
            __syncthreads();
            {
                int jj = tid >> 6, b = tid & 63;
                float lg = redB[0][jj][b] + redB[1][jj][b] + redB[2][jj][b] + redB[3][jj][b] + qb2[d0 + jj];
                lhist[((size_t)t * NSC + d0 + jj) * NB + b] = lg;
                unsigned bits = __float_as_uint(lg);
                unsigned key = (bits & 0x80000000u) ? ~bits : (bits | 0x80000000u);
                int cls = (d0 + jj) & 31;
                pkst[jj][b] = ((unsigned long long)key << 32) | (unsigned long long)(31 - cls);
            }
            __syncthreads();
            if (tid < 64) {
                unsigned long long m = pkst[0][tid];
                if (pkst[1][tid] > m) m = pkst[1][tid];
                if (pkst[2][tid] > m) m = pkst[2][tid];
                if (pkst[3][tid] > m) m = pkst[3][tid];
                atomicMax(&gmax[(d0 >> 5) * 64 + tid], m);
            }
        }
        grid.sync();  // S3
    }
    if (blk == 0 && tid < 64) {
        for (int g = 0; g < 32; ++g) {
            unsigned long long pk = gmax[g * 64 + tid];
            zidx[(NT - 1) * 32 * NB + g * NB + tid] = 31 - (int)((unsigned)pk & 31u);
        }
    }
}

// =================== K3a: prior w1 + LN stats ===================
__global__ __launch_bounds__(256) void k3_p1(const float* __restrict__ w1p,
                                             const float* __restrict__ b1p,
                                             float* __restrict__ ws)
{
    int blk = blockIdx.x;
    int t = blk >> 6, kg = blk & 63, k0 = kg * 16;
    int tid = threadIdx.x, w = tid >> 6, lane = tid & 63;
    const float* hrow = ws + O_HHIST + (size_t)t * ND * NB;
    float acc[16];
#pragma unroll
    for (int i = 0; i < 16; ++i) acc[i] = 0.f;
    int dd0 = w * 256;
    for (int d = dd0; d < dd0 + 256; ++d) {
        float hv = hrow[(size_t)d * NB + lane];
#pragma unroll
        for (int kk = 0; kk < 16; ++kk)
            acc[kk] = fmaf(w1p[(size_t)(k0 + kk) * ND + d], hv, acc[kk]);
    }
    __shared__ float red[4][16][64];
    __shared__ float vst[16][64];
#pragma unroll
    for (int kk = 0; kk < 16; ++kk) red[w][kk][lane] = acc[kk];
    __syncthreads();
    float* ph1 = ws + O_EPRE + (size_t)t * NH * NB;  // reuse E_pre region
    for (int q = 0; q < 4; ++q) {
        int slot = tid + q * 256;
        int kk = slot >> 6, b = slot & 63;
        float v = red[0][kk][b] + red[1][kk][b] + red[2][kk][b] + red[3][kk][b] + b1p[k0 + kk];
        ph1[(size_t)(k0 + kk) * NB + b] = v;
        vst[kk][b] = v;
    }
    __syncthreads();
    if (tid < 64) {
        float s1 = 0.f, s2 = 0.f;
#pragma unroll
        for (int kk = 0; kk < 16; ++kk) { float v = vst[kk][tid]; s1 += v; s2 = fmaf(v, v, s2); }
        float* pst = ws + O_PSTAT;
        atomicAdd(&pst[(t * NB + tid) * 2 + 0], s1);
        atomicAdd(&pst[(t * NB + tid) * 2 + 1], s2);
    }
}

// =================== K3b: prior LN+SiLU+w2 -> prior_logits ===================
__global__ __launch_bounds__(256) void k3_p2(const float* __restrict__ gp,
                                             const float* __restrict__ bep,
                                             const float* __restrict__ w2p,
                                             const float* __restrict__ b2p,
                                             float* __restrict__ ws,
                                             float* __restrict__ out)
{
    int blk = blockIdx.x;
    int t = blk >> 6, jg = blk & 63, j0 = jg * 16;
    int tid = threadIdx.x, w = tid >> 6, lane = tid & 63;
    const float* ph1 = ws + O_EPRE + (size_t)t * NH * NB;
    const float* pst = ws + O_PSTAT;
    __shared__ float smean[64], srstd[64];
    if (tid < 64) {
        float s1 = pst[(t * NB + tid) * 2], s2 = pst[(t * NB + tid) * 2 + 1];
        float mean = s1 * (1.f / NH);
        float var = s2 * (1.f / NH) - mean * mean;
        smean[tid] = mean;
        srstd[tid] = 1.f / sqrtf(var + EPS);
    }
    __syncthreads();
    float mean = smean[lane], rstd = srstd[lane];
    float acc[16];
#pragma unroll
    for (int i = 0; i < 16; ++i) acc[i] = 0.f;
    int kk0 = w * 256;
    for (int k = kk0; k < kk0 + 256; ++k) {
        float v = ph1[(size_t)k * NB + lane];
        float x = fmaf((v - mean) * rstd, gp[k], bep[k]);
        float s = x / (1.f + expf(-x));
#pragma unroll
        for (int jj = 0; jj < 16; ++jj)
            acc[jj] = fmaf(w2p[(size_t)(j0 + jj) * NH + k], s, acc[jj]);
    }
    __shared__ float red[4][16][64];
#pragma unroll
    for (int jj = 0; jj < 16; ++jj) red[w][jj][lane] = acc[jj];
    __syncthreads();
    float* prior = out + OUT_PRIOR;
    for (int q = 0; q < 4; ++q) {
        int slot = tid + q * 256;
        int b = slot >> 4, jj = slot & 15;
        float v = red[0][jj][b] + red[1][jj][b] + red[2][jj][b] + red[3][jj][b] + b2p[j0 + jj];
        prior[((size_t)b * NT + t) * NSC + j0 + jj] = v;
    }
}

// =================== K4: write-out transposes ===================
__global__ void k4_out(float* __restrict__ ws, float* __restrict__ out)
{
    int blk = blockIdx.x, tid = threadIdx.x;
    int rr = tid >> 6, ln = tid & 63;
    float* latent = out + OUT_LATENT;
    float* hseq = out + OUT_HSEQ;
    float* post = out + OUT_POST;
    if (blk < 1024) {
        int t = blk >> 4, dt = blk & 15, base_d = dt * 64;
        __shared__ float tile[64][65];
        const float* hh = ws + O_HHIST + (size_t)t * ND * NB;
        for (int q = 0; q < 16; ++q) {
            int row = q * 4 + rr;
            tile[row][ln] = hh[(size_t)(base_d + row) * NB + ln];
        }
        __syncthreads();
        for (int q = 0; q < 16; ++q) {
            int b = q * 4 + rr;
            float v = tile[ln][b];
            hseq[((size_t)b * NT + t) * ND + base_d + ln] = v;
            latent[((size_t)b * NT + t) * 2048 + base_d + ln] = v;
        }
    } else if (blk < 2048) {
        int bb = blk - 1024;
        int t = bb >> 4, jt = bb & 15, base_j = jt * 64;
        __shared__ float tile[64][65];
        const float* lh = ws + O_LHIST + (size_t)t * NSC * NB;
        for (int q = 0; q < 16; ++q) {
            int row = q * 4 + rr;
            tile[row][ln] = lh[(size_t)(base_j + row) * NB + ln];
        }
        __syncthreads();
        for (int q = 0; q < 16; ++q) {
            int b = q * 4 + rr;
            post[((size_t)b * NT + t) * NSC + base_j + ln] = tile[ln][b];
        }
    } else {
        int t = blk - 2048;
        const int* zi = (const int*)(ws + O_ZIDX) + t * 32 * NB;
        __shared__ int zl[32];
        for (int b = 0; b < NB; ++b) {
            if (tid < 32) zl[tid] = zi[tid * NB + b];
            __syncthreads();
            for (int q = 0; q < 4; ++q) {
                int j = q * 256 + tid;
                latent[((size_t)b * NT + t) * 2048 + 1024 + j] = (zl[j >> 5] == (j & 31)) ? 1.f : 0.f;
            }
            __syncthreads();
        }
    }
}

extern "C" void kernel_launch(void* const* d_in, const int* in_sizes, int n_in,
                              void* d_out, int out_size, void* d_ws, size_t ws_size,
                              hipStream_t stream)
{
    const float* embeds  = (const float*)d_in[0];
    const float* actions = (const float*)d_in[1];
    const int*   isfirst = (const int*)d_in[2];
    const float* Wih = (const float*)d_in[3];
    const float* Whh = (const float*)d_in[4];
    const float* bih = (const float*)d_in[5];
    const float* bhh = (const float*)d_in[6];
    const float* pw1r = (const float*)d_in[7];
    const float* pb1r = (const float*)d_in[8];
    const float* pgr  = (const float*)d_in[9];
    const float* pber = (const float*)d_in[10];
    const float* pw2r = (const float*)d_in[11];
    const float* pb2r = (const float*)d_in[12];
    const float* qw1 = (const float*)d_in[13];
    const float* qb1 = (const float*)d_in[14];
    const float* qg  = (const float*)d_in[15];
    const float* qbe = (const float*)d_in[16];
    const float* qw2 = (const float*)d_in[17];
    const float* qb2 = (const float*)d_in[18];
    float* out = (float*)d_out;
    float* ws = (float*)d_ws;

    hipLaunchKernelGGL(k0_prep, dim3(1538), dim3(256), 0, stream, embeds, actions, isfirst, ws);
    hipLaunchKernelGGL(k1_epre, dim3(4096), dim3(256), 0, stream, qw1, ws);

    void* args[] = {(void*)&Wih, (void*)&Whh, (void*)&bih, (void*)&bhh,
                    (void*)&qw1, (void*)&qb1, (void*)&qg, (void*)&qbe,
                    (void*)&qw2, (void*)&qb2, (void*)&ws};
    hipLaunchCooperativeKernel((void*)k2_scan, dim3(256), dim3(256), args, 0, stream);

    hipLaunchKernelGGL(k3_p1, dim3(4096), dim3(256), 0, stream, pw1r, pb1r, ws);
    hipLaunchKernelGGL(k3_p2, dim3(4096), dim3(256), 0, stream, pgr, pber, pw2r, pb2r, ws, out);
    hipLaunchKernelGGL(k4_out, dim3(2112), dim3(256), 0, stream, ws, out);
}

// Round 3
// 10403.686 us; speedup vs baseline: 2.3038x; 2.3038x over previous
//
#include <hip/hip_runtime.h>

#define NB 64      // batch
#define NT 64      // time
#define ND 1024    // DETER
#define NH 1024    // HID
#define NE 1536    // EMBED
#define NA 6       // ACT
#define NSC 1024   // STOCH*CLASSES
#define GIN 1030   // GRU_IN
#define W1STR 2560 // post_w1 row stride (ND+NE)
#define EPS 1e-5f

// ---- workspace layout (float offsets) ----
#define O_EPRE   0u            // [T][NH][NB]  (reused as ph1 by prior pass)
#define O_HHIST  4194304u      // [T][ND][NB]
#define O_LHIST  8388608u      // [T][NSC][NB] (post logits, [t][j][b])
#define O_EMBT   4194304u      // overlay on HHIST+LHIST pre-scan: [T][NE][NB]
#define O_BAR    12582912u     // barrier counter (u32) in old HKPP hole
#define O_PHT    12713984u     // [NH][NB]
#define O_GMAX   12812288u     // u64[32][NB] packed argmax
#define O_ZIDX   12816384u     // int[T][32][NB]
#define O_ACTT   12947456u     // [T][NA][NB]
#define O_KEEPT  12972032u     // [T][NB]
#define O_PSTAT  12976128u     // [T][NB][2] prior LN stats
// end: 12984320 floats = ~49.5 MB (same extent as R1)

// out layout (floats)
#define OUT_LATENT 0u
#define OUT_HSEQ   8388608u
#define OUT_POST   12582912u
#define OUT_PRIOR  16777216u

// ---- coherence-point bypass ops (agent scope, relaxed: no cache invalidation) ----
__device__ __forceinline__ float gload(const float* p) {
    return __uint_as_float(__hip_atomic_load((const unsigned int*)p,
                __ATOMIC_RELAXED, __HIP_MEMORY_SCOPE_AGENT));
}
__device__ __forceinline__ void gstoref(float* p, float v) {
    __hip_atomic_store((unsigned int*)p, __float_as_uint(v),
                __ATOMIC_RELAXED, __HIP_MEMORY_SCOPE_AGENT);
}
__device__ __forceinline__ unsigned long long gload64(const unsigned long long* p) {
    return __hip_atomic_load(p, __ATOMIC_RELAXED, __HIP_MEMORY_SCOPE_AGENT);
}
__device__ __forceinline__ void gstore64(unsigned long long* p, unsigned long long v) {
    __hip_atomic_store(p, v, __ATOMIC_RELAXED, __HIP_MEMORY_SCOPE_AGENT);
}

// monotone-counter grid barrier; no acquire fence -> L2 stays warm (weights!).
// per-wave vmcnt(0) before arrive = release for our sc-stores.
__device__ __forceinline__ void gbar(unsigned int* ctr, unsigned int target256) {
    asm volatile("s_waitcnt vmcnt(0) lgkmcnt(0)" ::: "memory");
    __syncthreads();
    if (threadIdx.x == 0) {
        __hip_atomic_fetch_add(ctr, 1u, __ATOMIC_RELAXED, __HIP_MEMORY_SCOPE_AGENT);
        while (__hip_atomic_load(ctr, __ATOMIC_RELAXED, __HIP_MEMORY_SCOPE_AGENT) < target256) {
            __builtin_amdgcn_s_sleep(1);
        }
    }
    __syncthreads();
}

// =================== K0: transposes + zero-init ===================
__global__ void k0_prep(const float* __restrict__ embeds,
                        const float* __restrict__ actions,
                        const int* __restrict__ isfirst,
                        float* __restrict__ ws)
{
    int blk = blockIdx.x, tid = threadIdx.x;
    int rr = tid >> 6, ln = tid & 63;
    if (blk < 1536) {
        // embeds (B,T,E) -> emb_T [t][e][b]
        int t = blk / 24, et = blk % 24, e0 = et * 64;
        __shared__ float tile[64][65];
        for (int q = 0; q < 16; ++q) {
            int b = q * 4 + rr;
            tile[b][ln] = embeds[((size_t)b * NT + t) * NE + e0 + ln];
        }
        __syncthreads();
        float* embT = ws + O_EMBT + (size_t)t * NE * NB;
        for (int q = 0; q < 16; ++q) {
            int e = q * 4 + rr;
            embT[(size_t)(e0 + e) * NB + ln] = tile[ln][e];
        }
    } else if (blk == 1536) {
        for (int i = tid; i < NT * NA * NB; i += 256) {
            int t = i / (NA * NB); int rem = i % (NA * NB);
            int a = rem / NB; int b = rem % NB;
            ws[O_ACTT + i] = actions[((size_t)b * NT + t) * NA + a];
        }
        for (int i = tid; i < NT * NB; i += 256) {
            int t = i / NB, b = i % NB;
            ws[O_KEEPT + i] = 1.f - (float)isfirst[(size_t)b * NT + t];
        }
    } else {
        if (tid == 0) *(unsigned int*)(ws + O_BAR) = 0u;
        for (int i = tid; i < NT * NB * 2; i += 256) ws[O_PSTAT + i] = 0.f;
    }
}

// =================== K1: E_pre = emb @ post_w1[:,1024:]^T ===================
__global__ __launch_bounds__(256) void k1_epre(const float* __restrict__ qw1,
                                               float* __restrict__ ws)
{
    int blk = blockIdx.x;
    int t = blk >> 6, kg = blk & 63, k0 = kg * 16;
    int tid = threadIdx.x, w = tid >> 6, lane = tid & 63;
    const float* embT = ws + O_EMBT + (size_t)t * NE * NB;
    float acc[16];
#pragma unroll
    for (int i = 0; i < 16; ++i) acc[i] = 0.f;
    int e0 = w * 384;
    for (int e = e0; e < e0 + 384; ++e) {
        float ev = embT[(size_t)e * NB + lane];
#pragma unroll
        for (int kk = 0; kk < 16; ++kk)
            acc[kk] = fmaf(qw1[(size_t)(k0 + kk) * W1STR + ND + e], ev, acc[kk]);
    }
    __shared__ float red[4][16][64];
#pragma unroll
    for (int kk = 0; kk < 16; ++kk) red[w][kk][lane] = acc[kk];
    __syncthreads();
    float* epre = ws + O_EPRE + (size_t)t * NH * NB;
    for (int q = 0; q < 4; ++q) {
        int slot = tid + q * 256;
        int kk = slot >> 6, b = slot & 63;
        float v = red[0][kk][b] + red[1][kk][b] + red[2][kk][b] + red[3][kk][b];
        epre[(size_t)(k0 + kk) * NB + b] = v;
    }
}

// =================== K2: the scan (manual barriers, L2-warm weights) ==========
// 256 blocks x 256 threads, 4 dims/block. Weights read with NORMAL cached
// loads (wave-uniform -> s_load, L2-resident: 32 blocks/XCD x 80KB = 2.6MB < 4MB).
// Cross-block data (h, phT, gmax) exchanged via agent-scope bypass ops only.
__global__ __launch_bounds__(256, 1)
void k2_scan(const float* __restrict__ Wih, const float* __restrict__ Whh,
             const float* __restrict__ bih, const float* __restrict__ bhh,
             const float* __restrict__ qw1, const float* __restrict__ qb1,
             const float* __restrict__ qg,  const float* __restrict__ qbe,
             const float* __restrict__ qw2, const float* __restrict__ qb2,
             float* __restrict__ ws)
{
    const int blk = blockIdx.x, tid = threadIdx.x;
    const int w = tid >> 6, lane = tid & 63;
    const int d0 = blk * 4;   // owned 4 dims (GRU dims / hid units / logit rows)
    const int dd = tid >> 6, bb = tid & 63;   // finalize mapping

    float* hhist = ws + O_HHIST;
    float* lhist = ws + O_LHIST;
    float* epre  = ws + O_EPRE;
    float* phT   = ws + O_PHT;
    unsigned int* ctr = (unsigned int*)(ws + O_BAR);
    unsigned long long* gmax = (unsigned long long*)(ws + O_GMAX);
    int* zidx = (int*)(ws + O_ZIDX);
    const float* actT  = ws + O_ACTT;
    const float* keepT = ws + O_KEEPT;

    __shared__ float sRed[4][4][64];
    __shared__ float smean[64], srstd[64];
    __shared__ unsigned long long pkst[4][64];

    unsigned int ep = 0;

    for (int t = 0; t < NT; ++t) {
        // ---------------- PHASE A: GRU -> h_new ----------------
        {
            float acc[12];
#pragma unroll
            for (int r = 0; r < 12; ++r) acc[r] = 0.f;
            if (t > 0) {
                const float* hp = hhist + (size_t)(t - 1) * ND * NB;
                int base = w * 256;
                float hbuf[32];
                for (int kt = 0; kt < 256; kt += 32) {
#pragma unroll
                    for (int j = 0; j < 32; ++j)
                        hbuf[j] = gload(hp + (size_t)(base + kt + j) * NB + lane);
#pragma unroll
                    for (int j = 0; j < 32; ++j) {
                        int k = base + kt + j;
                        float hv = hbuf[j];
#pragma unroll
                        for (int r = 0; r < 12; ++r) {
                            int row = (r >> 2) * 1024 + d0 + (r & 3);
                            acc[r] = fmaf(Whh[(size_t)row * ND + k], hv, acc[r]);
                        }
                    }
                }
            }
            float gh[3];
#pragma unroll
            for (int g2 = 0; g2 < 3; ++g2) {
#pragma unroll
                for (int q = 0; q < 4; ++q) sRed[w][q][lane] = acc[g2 * 4 + q];
                __syncthreads();
                gh[g2] = sRed[0][dd][bb] + sRed[1][dd][bb] + sRed[2][dd][bb] + sRed[3][dd][bb];
                __syncthreads();
            }
            {
                int d = d0 + dd;
                float keep = keepT[t * NB + bb];
                float ghr = fmaf(keep, gh[0], bhh[d]);
                float ghz = fmaf(keep, gh[1], bhh[1024 + d]);
                float ghn = fmaf(keep, gh[2], bhh[2048 + d]);
                float gxr = bih[d], gxz = bih[1024 + d], gxn = bih[2048 + d];
                if (t > 0) {
                    float sr = 0.f, sz = 0.f, sn = 0.f;
                    for (int g = 0; g < 32; ++g) {
                        unsigned long long pk = gload64(&gmax[g * 64 + bb]);
                        int c = 31 - (int)((unsigned)pk & 31u);
                        int col = g * 32 + c;
                        sr += Wih[(size_t)d * GIN + col];
                        sz += Wih[(size_t)(1024 + d) * GIN + col];
                        sn += Wih[(size_t)(2048 + d) * GIN + col];
                        if (blk == 0 && dd == 0) zidx[(t - 1) * 32 * NB + g * NB + bb] = c;
                    }
                    gxr = fmaf(keep, sr, gxr);
                    gxz = fmaf(keep, sz, gxz);
                    gxn = fmaf(keep, sn, gxn);
                }
#pragma unroll
                for (int a = 0; a < NA; ++a) {
                    float av = actT[(t * NA + a) * NB + bb];
                    gxr = fmaf(Wih[(size_t)d * GIN + ND + a], av, gxr);
                    gxz = fmaf(Wih[(size_t)(1024 + d) * GIN + ND + a], av, gxz);
                    gxn = fmaf(Wih[(size_t)(2048 + d) * GIN + ND + a], av, gxn);
                }
                float r = 1.f / (1.f + expf(-(gxr + ghr)));
                float u = 1.f / (1.f + expf(-(gxz + ghz)));
                float n = tanhf(gxn + r * ghn);
                float hprevm = (t > 0)
                    ? keep * gload(hhist + (size_t)(t - 1) * ND * NB + (size_t)d * NB + bb)
                    : 0.f;
                float hnew = (1.f - u) * n + u * hprevm;
                gstoref(&hhist[((size_t)t * ND + d) * NB + bb], hnew);
            }
        }
        gbar(ctr, ++ep * 256u);   // S1
        // ---------------- PHASE B: post w1 (h part) + E_pre -> phT ----------------
        {
            const float* hrow = hhist + (size_t)t * ND * NB;
            float acc4[4] = {0.f, 0.f, 0.f, 0.f};
            int base = w * 256;
            float hbuf[32];
            for (int kt = 0; kt < 256; kt += 32) {
#pragma unroll
                for (int j = 0; j < 32; ++j)
                    hbuf[j] = gload(hrow + (size_t)(base + kt + j) * NB + lane);
#pragma unroll
                for (int j = 0; j < 32; ++j) {
                    int k = base + kt + j;
#pragma unroll
                    for (int rr = 0; rr < 4; ++rr)
                        acc4[rr] = fmaf(qw1[(size_t)(d0 + rr) * W1STR + k], hbuf[j], acc4[rr]);
                }
            }
#pragma unroll
            for (int rr = 0; rr < 4; ++rr) sRed[w][rr][lane] = acc4[rr];
            if (blk == 0) {  // reset argmax accumulators (readers of old done at S1; C reads after S2)
                for (int i = tid; i < 2048; i += 256) gstore64(&gmax[i], 0ull);
            }
            __syncthreads();
            {
                float v = sRed[0][dd][bb] + sRed[1][dd][bb] + sRed[2][dd][bb] + sRed[3][dd][bb]
                        + qb1[d0 + dd] + epre[((size_t)t * NH + d0 + dd) * NB + bb];
                gstoref(&phT[(size_t)(d0 + dd) * NB + bb], v);
            }
        }
        gbar(ctr, ++ep * 256u);   // S2
        // ---------------- PHASE C: LN+SiLU+post w2 + argmax ----------------
        {
            int base = w * 256;
            float s1 = 0.f, s2 = 0.f;
            {
                float hbuf[32];
                for (int kt = 0; kt < 256; kt += 32) {
#pragma unroll
                    for (int j = 0; j < 32; ++j)
                        hbuf[j] = gload(phT + (size_t)(base + kt + j) * NB + lane);
#pragma unroll
                    for (int j = 0; j < 32; ++j) { s1 += hbuf[j]; s2 = fmaf(hbuf[j], hbuf[j], s2); }
                }
            }
            sRed[w][0][lane] = s1; sRed[w][1][lane] = s2;
            __syncthreads();
            if (tid < 64) {
                float a = sRed[0][0][tid] + sRed[1][0][tid] + sRed[2][0][tid] + sRed[3][0][tid];
                float q = sRed[0][1][tid] + sRed[1][1][tid] + sRed[2][1][tid] + sRed[3][1][tid];
                float mean = a * (1.f / NH);
                float var = q * (1.f / NH) - mean * mean;
                smean[tid] = mean;
                srstd[tid] = 1.f / sqrtf(var + EPS);
            }
            __syncthreads();
            float mean = smean[lane], rstd = srstd[lane];
            float acc4[4] = {0.f, 0.f, 0.f, 0.f};
            {
                float hbuf[32];
                for (int kt = 0; kt < 256; kt += 32) {
#pragma unroll
                    for (int j = 0; j < 32; ++j)
                        hbuf[j] = gload(phT + (size_t)(base + kt + j) * NB + lane);
#pragma unroll
                    for (int j = 0; j < 32; ++j) {
                        int k = base + kt + j;
                        float x = fmaf((hbuf[j] - mean) * rstd, qg[k], qbe[k]);
                        float sl = x / (1.f + expf(-x));
#pragma unroll
                        for (int jj = 0; jj < 4; ++jj)
                            acc4[jj] = fmaf(qw2[(size_t)(d0 + jj) * NH + k], sl, acc4[jj]);
                    }
                }
            }
            __syncthreads();
#pragma unroll
            for (int jj = 0; jj < 4; ++jj) sRed[w][jj][lane] = acc4[jj];
            __syncthreads();
            {
                float lg = sRed[0][dd][bb] + sRed[1][dd][bb] + sRed[2][dd][bb] + sRed[3][dd][bb]
                         + qb2[d0 + dd];
                lhist[((size_t)t * NSC + d0 + dd) * NB + bb] = lg;
                unsigned bits = __float_as_uint(lg);
                unsigned key = (bits & 0x80000000u) ? ~bits : (bits | 0x80000000u);
                int cls = (d0 + dd) & 31;
                pkst[dd][bb] = ((unsigned long long)key << 32) | (unsigned long long)(31 - cls);
            }
            __syncthreads();
            if (tid < 64) {
                unsigned long long m = pkst[0][tid];
                if (pkst[1][tid] > m) m = pkst[1][tid];
                if (pkst[2][tid] > m) m = pkst[2][tid];
                if (pkst[3][tid] > m) m = pkst[3][tid];
                __hip_atomic_fetch_max(&gmax[(d0 >> 5) * 64 + tid], m,
                                       __ATOMIC_RELAXED, __HIP_MEMORY_SCOPE_AGENT);
            }
        }
        gbar(ctr, ++ep * 256u);   // S3
    }
    if (blk == 0 && tid < 64) {
        for (int g = 0; g < 32; ++g) {
            unsigned long long pk = gload64(&gmax[g * 64 + tid]);
            zidx[(NT - 1) * 32 * NB + g * NB + tid] = 31 - (int)((unsigned)pk & 31u);
        }
    }
}

// =================== K3a: prior w1 + LN stats ===================
__global__ __launch_bounds__(256) void k3_p1(const float* __restrict__ w1p,
                                             const float* __restrict__ b1p,
                                             float* __restrict__ ws)
{
    int blk = blockIdx.x;
    int t = blk >> 6, kg = blk & 63, k0 = kg * 16;
    int tid = threadIdx.x, w = tid >> 6, lane = tid & 63;
    const float* hrow = ws + O_HHIST + (size_t)t * ND * NB;
    float acc[16];
#pragma unroll
    for (int i = 0; i < 16; ++i) acc[i] = 0.f;
    int dd0 = w * 256;
    for (int d = dd0; d < dd0 + 256; ++d) {
        float hv = hrow[(size_t)d * NB + lane];
#pragma unroll
        for (int kk = 0; kk < 16; ++kk)
            acc[kk] = fmaf(w1p[(size_t)(k0 + kk) * ND + d], hv, acc[kk]);
    }
    __shared__ float red[4][16][64];
    __shared__ float vst[16][64];
#pragma unroll
    for (int kk = 0; kk < 16; ++kk) red[w][kk][lane] = acc[kk];
    __syncthreads();
    float* ph1 = ws + O_EPRE + (size_t)t * NH * NB;  // reuse E_pre region
    for (int q = 0; q < 4; ++q) {
        int slot = tid + q * 256;
        int kk = slot >> 6, b = slot & 63;
        float v = red[0][kk][b] + red[1][kk][b] + red[2][kk][b] + red[3][kk][b] + b1p[k0 + kk];
        ph1[(size_t)(k0 + kk) * NB + b] = v;
        vst[kk][b] = v;
    }
    __syncthreads();
    if (tid < 64) {
        float s1 = 0.f, s2 = 0.f;
#pragma unroll
        for (int kk = 0; kk < 16; ++kk) { float v = vst[kk][tid]; s1 += v; s2 = fmaf(v, v, s2); }
        float* pst = ws + O_PSTAT;
        atomicAdd(&pst[(t * NB + tid) * 2 + 0], s1);
        atomicAdd(&pst[(t * NB + tid) * 2 + 1], s2);
    }
}

// =================== K3b: prior LN+SiLU+w2 -> prior_logits ===================
__global__ __launch_bounds__(256) void k3_p2(const float* __restrict__ gp,
                                             const float* __restrict__ bep,
                                             const float* __restrict__ w2p,
                                             const float* __restrict__ b2p,
                                             float* __restrict__ ws,
                                             float* __restrict__ out)
{
    int blk = blockIdx.x;
    int t = blk >> 6, jg = blk & 63, j0 = jg * 16;
    int tid = threadIdx.x, w = tid >> 6, lane = tid & 63;
    const float* ph1 = ws + O_EPRE + (size_t)t * NH * NB;
    const float* pst = ws + O_PSTAT;
    __shared__ float smean[64], srstd[64];
    if (tid < 64) {
        float s1 = pst[(t * NB + tid) * 2], s2 = pst[(t * NB + tid) * 2 + 1];
        float mean = s1 * (1.f / NH);
        float var = s2 * (1.f / NH) - mean * mean;
        smean[tid] = mean;
        srstd[tid] = 1.f / sqrtf(var + EPS);
    }
    __syncthreads();
    float mean = smean[lane], rstd = srstd[lane];
    float acc[16];
#pragma unroll
    for (int i = 0; i < 16; ++i) acc[i] = 0.f;
    int kk0 = w * 256;
    for (int k = kk0; k < kk0 + 256; ++k) {
        float v = ph1[(size_t)k * NB + lane];
        float x = fmaf((v - mean) * rstd, gp[k], bep[k]);
        float s = x / (1.f + expf(-x));
#pragma unroll
        for (int jj = 0; jj < 16; ++jj)
            acc[jj] = fmaf(w2p[(size_t)(j0 + jj) * NH + k], s, acc[jj]);
    }
    __shared__ float red[4][16][64];
#pragma unroll
    for (int jj = 0; jj < 16; ++jj) red[w][jj][lane] = acc[jj];
    __syncthreads();
    float* prior = out + OUT_PRIOR;
    for (int q = 0; q < 4; ++q) {
        int slot = tid + q * 256;
        int b = slot >> 4, jj = slot & 15;
        float v = red[0][jj][b] + red[1][jj][b] + red[2][jj][b] + red[3][jj][b] + b2p[j0 + jj];
        prior[((size_t)b * NT + t) * NSC + j0 + jj] = v;
    }
}

// =================== K4: write-out transposes ===================
__global__ void k4_out(float* __restrict__ ws, float* __restrict__ out)
{
    int blk = blockIdx.x, tid = threadIdx.x;
    int rr = tid >> 6, ln = tid & 63;
    float* latent = out + OUT_LATENT;
    float* hseq = out + OUT_HSEQ;
    float* post = out + OUT_POST;
    if (blk < 1024) {
        int t = blk >> 4, dt = blk & 15, base_d = dt * 64;
        __shared__ float tile[64][65];
        const float* hh = ws + O_HHIST + (size_t)t * ND * NB;
        for (int q = 0; q < 16; ++q) {
            int row = q * 4 + rr;
            tile[row][ln] = hh[(size_t)(base_d + row) * NB + ln];
        }
        __syncthreads();
        for (int q = 0; q < 16; ++q) {
            int b = q * 4 + rr;
            float v = tile[ln][b];
            hseq[((size_t)b * NT + t) * ND + base_d + ln] = v;
            latent[((size_t)b * NT + t) * 2048 + base_d + ln] = v;
        }
    } else if (blk < 2048) {
        int bb = blk - 1024;
        int t = bb >> 4, jt = bb & 15, base_j = jt * 64;
        __shared__ float tile[64][65];
        const float* lh = ws + O_LHIST + (size_t)t * NSC * NB;
        for (int q = 0; q < 16; ++q) {
            int row = q * 4 + rr;
            tile[row][ln] = lh[(size_t)(base_j + row) * NB + ln];
        }
        __syncthreads();
        for (int q = 0; q < 16; ++q) {
            int b = q * 4 + rr;
            post[((size_t)b * NT + t) * NSC + base_j + ln] = tile[ln][b];
        }
    } else {
        int t = blk - 2048;
        const int* zi = (const int*)(ws + O_ZIDX) + t * 32 * NB;
        __shared__ int zl[32];
        for (int b = 0; b < NB; ++b) {
            if (tid < 32) zl[tid] = zi[tid * NB + b];
            __syncthreads();
            for (int q = 0; q < 4; ++q) {
                int j = q * 256 + tid;
                latent[((size_t)b * NT + t) * 2048 + 1024 + j] = (zl[j >> 5] == (j & 31)) ? 1.f : 0.f;
            }
            __syncthreads();
        }
    }
}

extern "C" void kernel_launch(void* const* d_in, const int* in_sizes, int n_in,
                              void* d_out, int out_size, void* d_ws, size_t ws_size,
                              hipStream_t stream)
{
    const float* embeds  = (const float*)d_in[0];
    const float* actions = (const float*)d_in[1];
    const int*   isfirst = (const int*)d_in[2];
    const float* Wih = (const float*)d_in[3];
    const float* Whh = (const float*)d_in[4];
    const float* bih = (const float*)d_in[5];
    const float* bhh = (const float*)d_in[6];
    const float* pw1r = (const float*)d_in[7];
    const float* pb1r = (const float*)d_in[8];
    const float* pgr  = (const float*)d_in[9];
    const float* pber = (const float*)d_in[10];
    const float* pw2r = (const float*)d_in[11];
    const float* pb2r = (const float*)d_in[12];
    const float* qw1 = (const float*)d_in[13];
    const float* qb1 = (const float*)d_in[14];
    const float* qg  = (const float*)d_in[15];
    const float* qbe = (const float*)d_in[16];
    const float* qw2 = (const float*)d_in[17];
    const float* qb2 = (const float*)d_in[18];
    float* out = (float*)d_out;
    float* ws = (float*)d_ws;

    hipLaunchKernelGGL(k0_prep, dim3(1538), dim3(256), 0, stream, embeds, actions, isfirst, ws);
    hipLaunchKernelGGL(k1_epre, dim3(4096), dim3(256), 0, stream, qw1, ws);

    void* args[] = {(void*)&Wih, (void*)&Whh, (void*)&bih, (void*)&bhh,
                    (void*)&qw1, (void*)&qb1, (void*)&qg, (void*)&qbe,
                    (void*)&qw2, (void*)&qb2, (void*)&ws};
    hipLaunchCooperativeKernel((void*)k2_scan, dim3(256), dim3(256), args, 0, stream);

    hipLaunchKernelGGL(k3_p1, dim3(4096), dim3(256), 0, stream, pw1r, pb1r, ws);
    hipLaunchKernelGGL(k3_p2, dim3(4096), dim3(256), 0, stream, pgr, pber, pw2r, pb2r, ws, out);
    hipLaunchKernelGGL(k4_out, dim3(2112), dim3(256), 0, stream, ws, out);
}

// Round 4
// 10085.067 us; speedup vs baseline: 2.3766x; 1.0316x over previous
//
#include <hip/hip_runtime.h>

#define NB 64      // batch
#define NT 64      // time
#define ND 1024    // DETER
#define NH 1024    // HID
#define NE 1536    // EMBED
#define NA 6       // ACT
#define NSC 1024   // STOCH*CLASSES
#define GIN 1030   // GRU_IN
#define W1STR 2560 // post_w1 row stride (ND+NE)
#define EPS 1e-5f

// ---- workspace layout (float offsets) ----
#define O_EPRE   0u            // [T][NH][NB]  epre, then phT[t] in-place, then k3 ph1
#define O_HHIST  4194304u      // [T][ND][NB]
#define O_LHIST  8388608u      // [T][NSC][NB] (post logits, [t][j][b])
#define O_EMBT   4194304u      // overlay on HHIST+LHIST pre-scan: [T][NE][NB]
#define O_BAR    12582912u     // barrier counter (u32)
#define O_PSTT   12582976u     // [T][NB][2] post LN stats (scan)
#define O_PHT    12713984u     // (unused now)
#define O_GMAX   12812288u     // u64[32][NB] packed argmax
#define O_ZIDX   12816384u     // int[T][32][NB]
#define O_ACTT   12947456u     // [T][NA][NB]
#define O_KEEPT  12972032u     // [T][NB]
#define O_PSTAT  12976128u     // [T][NB][2] prior LN stats (k3)
// end: 12984320 floats = ~49.5 MB (same extent as R1/R3)

// out layout (floats)
#define OUT_LATENT 0u
#define OUT_HSEQ   8388608u
#define OUT_POST   12582912u
#define OUT_PRIOR  16777216u

// ---- coherence-point bypass ops (agent scope, relaxed) ----
__device__ __forceinline__ float gload(const float* p) {
    return __uint_as_float(__hip_atomic_load((const unsigned int*)p,
                __ATOMIC_RELAXED, __HIP_MEMORY_SCOPE_AGENT));
}
__device__ __forceinline__ void gstoref(float* p, float v) {
    __hip_atomic_store((unsigned int*)p, __float_as_uint(v),
                __ATOMIC_RELAXED, __HIP_MEMORY_SCOPE_AGENT);
}
__device__ __forceinline__ unsigned long long gload64(const unsigned long long* p) {
    return __hip_atomic_load(p, __ATOMIC_RELAXED, __HIP_MEMORY_SCOPE_AGENT);
}
__device__ __forceinline__ void gstore64(unsigned long long* p, unsigned long long v) {
    __hip_atomic_store(p, v, __ATOMIC_RELAXED, __HIP_MEMORY_SCOPE_AGENT);
}

// monotone-counter grid barrier; relaxed (no L2 invalidation).
__device__ __forceinline__ void gbar(unsigned int* ctr, unsigned int target) {
    asm volatile("s_waitcnt vmcnt(0) lgkmcnt(0)" ::: "memory");
    __syncthreads();
    if (threadIdx.x == 0) {
        __hip_atomic_fetch_add(ctr, 1u, __ATOMIC_RELAXED, __HIP_MEMORY_SCOPE_AGENT);
        while (__hip_atomic_load(ctr, __ATOMIC_RELAXED, __HIP_MEMORY_SCOPE_AGENT) < target) {
            __builtin_amdgcn_s_sleep(1);
        }
    }
    __syncthreads();
}

// =================== K0: transposes + zero-init ===================
__global__ void k0_prep(const float* __restrict__ embeds,
                        const float* __restrict__ actions,
                        const int* __restrict__ isfirst,
                        float* __restrict__ ws)
{
    int blk = blockIdx.x, tid = threadIdx.x;
    int rr = tid >> 6, ln = tid & 63;
    if (blk < 1536) {
        // embeds (B,T,E) -> emb_T [t][e][b]
        int t = blk / 24, et = blk % 24, e0 = et * 64;
        __shared__ float tile[64][65];
        for (int q = 0; q < 16; ++q) {
            int b = q * 4 + rr;
            tile[b][ln] = embeds[((size_t)b * NT + t) * NE + e0 + ln];
        }
        __syncthreads();
        float* embT = ws + O_EMBT + (size_t)t * NE * NB;
        for (int q = 0; q < 16; ++q) {
            int e = q * 4 + rr;
            embT[(size_t)(e0 + e) * NB + ln] = tile[ln][e];
        }
    } else if (blk == 1536) {
        for (int i = tid; i < NT * NA * NB; i += 256) {
            int t = i / (NA * NB); int rem = i % (NA * NB);
            int a = rem / NB; int b = rem % NB;
            ws[O_ACTT + i] = actions[((size_t)b * NT + t) * NA + a];
        }
        for (int i = tid; i < NT * NB; i += 256) {
            int t = i / NB, b = i % NB;
            ws[O_KEEPT + i] = 1.f - (float)isfirst[(size_t)b * NT + t];
        }
    } else {
        if (tid == 0) *(unsigned int*)(ws + O_BAR) = 0u;
        for (int i = tid; i < NT * NB * 2; i += 256) {
            ws[O_PSTAT + i] = 0.f;
            ws[O_PSTT + i] = 0.f;
        }
    }
}

// =================== K1: E_pre = emb @ post_w1[:,1024:]^T ===================
__global__ __launch_bounds__(256) void k1_epre(const float* __restrict__ qw1,
                                               float* __restrict__ ws)
{
    int blk = blockIdx.x;
    int t = blk >> 6, kg = blk & 63, k0 = kg * 16;
    int tid = threadIdx.x, w = tid >> 6, lane = tid & 63;
    const float* embT = ws + O_EMBT + (size_t)t * NE * NB;
    float acc[16];
#pragma unroll
    for (int i = 0; i < 16; ++i) acc[i] = 0.f;
    int e0 = w * 384;
    for (int e = e0; e < e0 + 384; ++e) {
        float ev = embT[(size_t)e * NB + lane];
#pragma unroll
        for (int kk = 0; kk < 16; ++kk)
            acc[kk] = fmaf(qw1[(size_t)(k0 + kk) * W1STR + ND + e], ev, acc[kk]);
    }
    __shared__ float red[4][16][64];
#pragma unroll
    for (int kk = 0; kk < 16; ++kk) red[w][kk][lane] = acc[kk];
    __syncthreads();
    float* epre = ws + O_EPRE + (size_t)t * NH * NB;
    for (int q = 0; q < 4; ++q) {
        int slot = tid + q * 256;
        int kk = slot >> 6, b = slot & 63;
        float v = red[0][kk][b] + red[1][kk][b] + red[2][kk][b] + red[3][kk][b];
        epre[(size_t)(k0 + kk) * NB + b] = v;
    }
}

// =================== K2: the scan ===================
// 256 blocks x 512 threads (8 waves/CU). Manual relaxed barriers.
// Activations: t-indexed addresses -> NORMAL cached reads are safe (first
// normal touch happens after the bypass write; dispatch acquire cleaned L2).
// Writes that cross XCDs stay bypass (sc) so data lands at L3.
__global__ __launch_bounds__(512, 2)
void k2_scan(const float* __restrict__ Wih, const float* __restrict__ Whh,
             const float* __restrict__ bih, const float* __restrict__ bhh,
             const float* __restrict__ qw1, const float* __restrict__ qb1,
             const float* __restrict__ qg,  const float* __restrict__ qbe,
             const float* __restrict__ qw2, const float* __restrict__ qb2,
             float* __restrict__ ws)
{
    const int blk = blockIdx.x, tid = threadIdx.x;
    const int w = tid >> 6, lane = tid & 63;
    const int d0 = blk * 4;                    // owned 4 dims
    const int dd = (tid >> 6) & 3, bb = tid & 63;  // finalize mapping (tid<256)

    float* hhist = ws + O_HHIST;
    float* lhist = ws + O_LHIST;
    float* epre  = ws + O_EPRE;          // also phT[t] in-place
    float* pstt  = ws + O_PSTT;
    unsigned int* ctr = (unsigned int*)(ws + O_BAR);
    unsigned long long* gmax = (unsigned long long*)(ws + O_GMAX);
    int* zidx = (int*)(ws + O_ZIDX);
    const float* actT  = ws + O_ACTT;
    const float* keepT = ws + O_KEEPT;

    __shared__ float sRed[8][4][64];
    __shared__ float sV[4][64];
    __shared__ float smean[64], srstd[64];
    __shared__ unsigned long long pkst[4][64];

    unsigned int ep = 0;

    for (int t = 0; t < NT; ++t) {
        // ---------------- PHASE A: GRU -> h_new ----------------
        {
            float acc[12];
#pragma unroll
            for (int r = 0; r < 12; ++r) acc[r] = 0.f;
            if (t > 0) {
                const float* hp = hhist + (size_t)(t - 1) * ND * NB;  // normal reads (L2-warm)
                int base = w * 128;
                for (int kt = 0; kt < 128; kt += 16) {
                    float hbuf[16];
#pragma unroll
                    for (int j = 0; j < 16; ++j)
                        hbuf[j] = hp[(size_t)(base + kt + j) * NB + lane];
#pragma unroll
                    for (int j = 0; j < 16; ++j) {
                        int k = base + kt + j;
#pragma unroll
                        for (int r = 0; r < 12; ++r) {
                            int row = (r >> 2) * 1024 + d0 + (r & 3);
                            acc[r] = fmaf(Whh[(size_t)row * ND + k], hbuf[j], acc[r]);
                        }
                    }
                }
            }
            float gh[3] = {0.f, 0.f, 0.f};
#pragma unroll
            for (int g2 = 0; g2 < 3; ++g2) {
                __syncthreads();
#pragma unroll
                for (int q = 0; q < 4; ++q) sRed[w][q][lane] = acc[g2 * 4 + q];
                __syncthreads();
                if (tid < 256) {
                    float s = 0.f;
#pragma unroll
                    for (int ww = 0; ww < 8; ++ww) s += sRed[ww][dd][bb];
                    gh[g2] = s;
                }
            }
            if (tid < 256) {
                int d = d0 + dd;
                float keep = keepT[t * NB + bb];
                float ghr = fmaf(keep, gh[0], bhh[d]);
                float ghz = fmaf(keep, gh[1], bhh[1024 + d]);
                float ghn = fmaf(keep, gh[2], bhh[2048 + d]);
                float gxr = bih[d], gxz = bih[1024 + d], gxn = bih[2048 + d];
                if (t > 0) {
                    unsigned long long pkbuf[32];
#pragma unroll 8
                    for (int g = 0; g < 32; ++g)
                        pkbuf[g] = gload64(&gmax[g * 64 + bb]);
                    float sr = 0.f, sz = 0.f, sn = 0.f;
#pragma unroll 8
                    for (int g = 0; g < 32; ++g) {
                        int c = 31 - (int)((unsigned)pkbuf[g] & 31u);
                        int col = g * 32 + c;
                        sr += Wih[(size_t)d * GIN + col];
                        sz += Wih[(size_t)(1024 + d) * GIN + col];
                        sn += Wih[(size_t)(2048 + d) * GIN + col];
                        if (blk == 0 && dd == 0) zidx[(t - 1) * 32 * NB + g * NB + bb] = c;
                    }
                    gxr = fmaf(keep, sr, gxr);
                    gxz = fmaf(keep, sz, gxz);
                    gxn = fmaf(keep, sn, gxn);
                }
#pragma unroll
                for (int a = 0; a < NA; ++a) {
                    float av = actT[(t * NA + a) * NB + bb];
                    gxr = fmaf(Wih[(size_t)d * GIN + ND + a], av, gxr);
                    gxz = fmaf(Wih[(size_t)(1024 + d) * GIN + ND + a], av, gxz);
                    gxn = fmaf(Wih[(size_t)(2048 + d) * GIN + ND + a], av, gxn);
                }
                float r = 1.f / (1.f + __expf(-(gxr + ghr)));
                float u = 1.f / (1.f + __expf(-(gxz + ghz)));
                float n = tanhf(gxn + r * ghn);
                float hprevm = 0.f;
                if (t > 0)
                    hprevm = keep * hhist[((size_t)(t - 1) * ND + d) * NB + bb];  // L2-warm
                float hnew = (1.f - u) * n + u * hprevm;
                gstoref(&hhist[((size_t)t * ND + d) * NB + bb], hnew);  // bypass -> L3
            }
        }
        gbar(ctr, ++ep * 256u);   // S1
        // -------- PHASE B: post w1 (h part) + E_pre -> phT (in epre[t]) + stats --------
        {
            const float* hrow = hhist + (size_t)t * ND * NB;   // normal (first touch fresh)
            float acc4[4] = {0.f, 0.f, 0.f, 0.f};
            int base = w * 128;
            for (int kt = 0; kt < 128; kt += 16) {
                float hbuf[16];
#pragma unroll
                for (int j = 0; j < 16; ++j)
                    hbuf[j] = hrow[(size_t)(base + kt + j) * NB + lane];
#pragma unroll
                for (int j = 0; j < 16; ++j) {
                    int k = base + kt + j;
#pragma unroll
                    for (int rr = 0; rr < 4; ++rr)
                        acc4[rr] = fmaf(qw1[(size_t)(d0 + rr) * W1STR + k], hbuf[j], acc4[rr]);
                }
            }
            __syncthreads();
#pragma unroll
            for (int rr = 0; rr < 4; ++rr) sRed[w][rr][lane] = acc4[rr];
            if (blk == 0 && tid >= 256) {   // reset argmax accumulators (waves 4-7)
                for (int i = tid - 256; i < 2048; i += 256) gstore64(&gmax[i], 0ull);
            }
            __syncthreads();
            if (tid < 256) {
                float s = 0.f;
#pragma unroll
                for (int ww = 0; ww < 8; ++ww) s += sRed[ww][dd][bb];
                size_t idx = ((size_t)t * NH + d0 + dd) * NB + bb;
                float v = s + qb1[d0 + dd] + gload(&epre[idx]);   // bypass read (no L2 alloc)
                gstoref(&epre[idx], v);                           // bypass write -> L3
                sV[dd][bb] = v;
            }
            __syncthreads();
            if (tid < 64) {
                float a = sV[0][tid], b2 = sV[1][tid], c = sV[2][tid], e = sV[3][tid];
                float s1 = a + b2 + c + e;
                float s2 = fmaf(a, a, fmaf(b2, b2, fmaf(c, c, e * e)));
                __hip_atomic_fetch_add(&pstt[(t * NB + tid) * 2 + 0], s1,
                                       __ATOMIC_RELAXED, __HIP_MEMORY_SCOPE_AGENT);
                __hip_atomic_fetch_add(&pstt[(t * NB + tid) * 2 + 1], s2,
                                       __ATOMIC_RELAXED, __HIP_MEMORY_SCOPE_AGENT);
            }
        }
        gbar(ctr, ++ep * 256u);   // S2
        // ---------------- PHASE C: LN+SiLU+post w2 + argmax ----------------
        {
            if (tid < 64) {
                float s1 = gload(&pstt[(t * NB + tid) * 2 + 0]);
                float s2 = gload(&pstt[(t * NB + tid) * 2 + 1]);
                float mean = s1 * (1.f / NH);
                float var = s2 * (1.f / NH) - mean * mean;
                smean[tid] = mean;
                srstd[tid] = 1.f / sqrtf(var + EPS);
            }
            __syncthreads();
            float mean = smean[lane], rstd = srstd[lane];
            const float* phTn = epre + (size_t)t * NH * NB;    // NORMAL reads (fresh lines)
            float acc4[4] = {0.f, 0.f, 0.f, 0.f};
            int base = w * 128;
            for (int kt = 0; kt < 128; kt += 16) {
                float hbuf[16];
#pragma unroll
                for (int j = 0; j < 16; ++j)
                    hbuf[j] = phTn[(size_t)(base + kt + j) * NB + lane];
#pragma unroll
                for (int j = 0; j < 16; ++j) {
                    int k = base + kt + j;
                    float x = fmaf((hbuf[j] - mean) * rstd, qg[k], qbe[k]);
                    float sl = x / (1.f + __expf(-x));
#pragma unroll
                    for (int jj = 0; jj < 4; ++jj)
                        acc4[jj] = fmaf(qw2[(size_t)(d0 + jj) * NH + k], sl, acc4[jj]);
                }
            }
            __syncthreads();
#pragma unroll
            for (int jj = 0; jj < 4; ++jj) sRed[w][jj][lane] = acc4[jj];
            __syncthreads();
            if (tid < 256) {
                float s = 0.f;
#pragma unroll
                for (int ww = 0; ww < 8; ++ww) s += sRed[ww][dd][bb];
                float lg = s + qb2[d0 + dd];
                lhist[((size_t)t * NSC + d0 + dd) * NB + bb] = lg;   // normal store
                unsigned bits = __float_as_uint(lg);
                unsigned key = (bits & 0x80000000u) ? ~bits : (bits | 0x80000000u);
                int cls = (d0 + dd) & 31;
                pkst[dd][bb] = ((unsigned long long)key << 32) | (unsigned long long)(31 - cls);
            }
            __syncthreads();
            if (tid < 64) {
                unsigned long long m = pkst[0][tid];
                if (pkst[1][tid] > m) m = pkst[1][tid];
                if (pkst[2][tid] > m) m = pkst[2][tid];
                if (pkst[3][tid] > m) m = pkst[3][tid];
                __hip_atomic_fetch_max(&gmax[(d0 >> 5) * 64 + tid], m,
                                       __ATOMIC_RELAXED, __HIP_MEMORY_SCOPE_AGENT);
            }
        }
        gbar(ctr, ++ep * 256u);   // S3
    }
    if (blk == 0 && tid < 64) {
        for (int g = 0; g < 32; ++g) {
            unsigned long long pk = gload64(&gmax[g * 64 + tid]);
            zidx[(NT - 1) * 32 * NB + g * NB + tid] = 31 - (int)((unsigned)pk & 31u);
        }
    }
}

// =================== K3a: prior w1 + LN stats ===================
__global__ __launch_bounds__(256) void k3_p1(const float* __restrict__ w1p,
                                             const float* __restrict__ b1p,
                                             float* __restrict__ ws)
{
    int blk = blockIdx.x;
    int t = blk >> 6, kg = blk & 63, k0 = kg * 16;
    int tid = threadIdx.x, w = tid >> 6, lane = tid & 63;
    const float* hrow = ws + O_HHIST + (size_t)t * ND * NB;
    float acc[16];
#pragma unroll
    for (int i = 0; i < 16; ++i) acc[i] = 0.f;
    int dd0 = w * 256;
    for (int d = dd0; d < dd0 + 256; ++d) {
        float hv = hrow[(size_t)d * NB + lane];
#pragma unroll
        for (int kk = 0; kk < 16; ++kk)
            acc[kk] = fmaf(w1p[(size_t)(k0 + kk) * ND + d], hv, acc[kk]);
    }
    __shared__ float red[4][16][64];
    __shared__ float vst[16][64];
#pragma unroll
    for (int kk = 0; kk < 16; ++kk) red[w][kk][lane] = acc[kk];
    __syncthreads();
    float* ph1 = ws + O_EPRE + (size_t)t * NH * NB;  // reuse E_pre region
    for (int q = 0; q < 4; ++q) {
        int slot = tid + q * 256;
        int kk = slot >> 6, b = slot & 63;
        float v = red[0][kk][b] + red[1][kk][b] + red[2][kk][b] + red[3][kk][b] + b1p[k0 + kk];
        ph1[(size_t)(k0 + kk) * NB + b] = v;
        vst[kk][b] = v;
    }
    __syncthreads();
    if (tid < 64) {
        float s1 = 0.f, s2 = 0.f;
#pragma unroll
        for (int kk = 0; kk < 16; ++kk) { float v = vst[kk][tid]; s1 += v; s2 = fmaf(v, v, s2); }
        float* pst = ws + O_PSTAT;
        atomicAdd(&pst[(t * NB + tid) * 2 + 0], s1);
        atomicAdd(&pst[(t * NB + tid) * 2 + 1], s2);
    }
}

// =================== K3b: prior LN+SiLU+w2 -> prior_logits ===================
__global__ __launch_bounds__(256) void k3_p2(const float* __restrict__ gp,
                                             const float* __restrict__ bep,
                                             const float* __restrict__ w2p,
                                             const float* __restrict__ b2p,
                                             float* __restrict__ ws,
                                             float* __restrict__ out)
{
    int blk = blockIdx.x;
    int t = blk >> 6, jg = blk & 63, j0 = jg * 16;
    int tid = threadIdx.x, w = tid >> 6, lane = tid & 63;
    const float* ph1 = ws + O_EPRE + (size_t)t * NH * NB;
    const float* pst = ws + O_PSTAT;
    __shared__ float smean[64], srstd[64];
    if (tid < 64) {
        float s1 = pst[(t * NB + tid) * 2], s2 = pst[(t * NB + tid) * 2 + 1];
        float mean = s1 * (1.f / NH);
        float var = s2 * (1.f / NH) - mean * mean;
        smean[tid] = mean;
        srstd[tid] = 1.f / sqrtf(var + EPS);
    }
    __syncthreads();
    float mean = smean[lane], rstd = srstd[lane];
    float acc[16];
#pragma unroll
    for (int i = 0; i < 16; ++i) acc[i] = 0.f;
    int kk0 = w * 256;
    for (int k = kk0; k < kk0 + 256; ++k) {
        float v = ph1[(size_t)k * NB + lane];
        float x = fmaf((v - mean) * rstd, gp[k], bep[k]);
        float s = x / (1.f + __expf(-x));
#pragma unroll
        for (int jj = 0; jj < 16; ++jj)
            acc[jj] = fmaf(w2p[(size_t)(j0 + jj) * NH + k], s, acc[jj]);
    }
    __shared__ float red[4][16][64];
#pragma unroll
    for (int jj = 0; jj < 16; ++jj) red[w][jj][lane] = acc[jj];
    __syncthreads();
    float* prior = out + OUT_PRIOR;
    for (int q = 0; q < 4; ++q) {
        int slot = tid + q * 256;
        int b = slot >> 4, jj = slot & 15;
        float v = red[0][jj][b] + red[1][jj][b] + red[2][jj][b] + red[3][jj][b] + b2p[j0 + jj];
        prior[((size_t)b * NT + t) * NSC + j0 + jj] = v;
    }
}

// =================== K4: write-out transposes ===================
__global__ void k4_out(float* __restrict__ ws, float* __restrict__ out)
{
    int blk = blockIdx.x, tid = threadIdx.x;
    int rr = tid >> 6, ln = tid & 63;
    float* latent = out + OUT_LATENT;
    float* hseq = out + OUT_HSEQ;
    float* post = out + OUT_POST;
    if (blk < 1024) {
        int t = blk >> 4, dt = blk & 15, base_d = dt * 64;
        __shared__ float tile[64][65];
        const float* hh = ws + O_HHIST + (size_t)t * ND * NB;
        for (int q = 0; q < 16; ++q) {
            int row = q * 4 + rr;
            tile[row][ln] = hh[(size_t)(base_d + row) * NB + ln];
        }
        __syncthreads();
        for (int q = 0; q < 16; ++q) {
            int b = q * 4 + rr;
            float v = tile[ln][b];
            hseq[((size_t)b * NT + t) * ND + base_d + ln] = v;
            latent[((size_t)b * NT + t) * 2048 + base_d + ln] = v;
        }
    } else if (blk < 2048) {
        int bb = blk - 1024;
        int t = bb >> 4, jt = bb & 15, base_j = jt * 64;
        __shared__ float tile[64][65];
        const float* lh = ws + O_LHIST + (size_t)t * NSC * NB;
        for (int q = 0; q < 16; ++q) {
            int row = q * 4 + rr;
            tile[row][ln] = lh[(size_t)(base_j + row) * NB + ln];
        }
        __syncthreads();
        for (int q = 0; q < 16; ++q) {
            int b = q * 4 + rr;
            post[((size_t)b * NT + t) * NSC + base_j + ln] = tile[ln][b];
        }
    } else {
        int t = blk - 2048;
        const int* zi = (const int*)(ws + O_ZIDX) + t * 32 * NB;
        __shared__ int zl[32];
        for (int b = 0; b < NB; ++b) {
            if (tid < 32) zl[tid] = zi[tid * NB + b];
            __syncthreads();
            for (int q = 0; q < 4; ++q) {
                int j = q * 256 + tid;
                latent[((size_t)b * NT + t) * 2048 + 1024 + j] = (zl[j >> 5] == (j & 31)) ? 1.f : 0.f;
            }
            __syncthreads();
        }
    }
}

extern "C" void kernel_launch(void* const* d_in, const int* in_sizes, int n_in,
                              void* d_out, int out_size, void* d_ws, size_t ws_size,
                              hipStream_t stream)
{
    const float* embeds  = (const float*)d_in[0];
    const float* actions = (const float*)d_in[1];
    const int*   isfirst = (const int*)d_in[2];
    const float* Wih = (const float*)d_in[3];
    const float* Whh = (const float*)d_in[4];
    const float* bih = (const float*)d_in[5];
    const float* bhh = (const float*)d_in[6];
    const float* pw1r = (const float*)d_in[7];
    const float* pb1r = (const float*)d_in[8];
    const float* pgr  = (const float*)d_in[9];
    const float* pber = (const float*)d_in[10];
    const float* pw2r = (const float*)d_in[11];
    const float* pb2r = (const float*)d_in[12];
    const float* qw1 = (const float*)d_in[13];
    const float* qb1 = (const float*)d_in[14];
    const float* qg  = (const float*)d_in[15];
    const float* qbe = (const float*)d_in[16];
    const float* qw2 = (const float*)d_in[17];
    const float* qb2 = (const float*)d_in[18];
    float* out = (float*)d_out;
    float* ws = (float*)d_ws;

    hipLaunchKernelGGL(k0_prep, dim3(1538), dim3(256), 0, stream, embeds, actions, isfirst, ws);
    hipLaunchKernelGGL(k1_epre, dim3(4096), dim3(256), 0, stream, qw1, ws);

    void* args[] = {(void*)&Wih, (void*)&Whh, (void*)&bih, (void*)&bhh,
                    (void*)&qw1, (void*)&qb1, (void*)&qg, (void*)&qbe,
                    (void*)&qw2, (void*)&qb2, (void*)&ws};
    hipLaunchCooperativeKernel((void*)k2_scan, dim3(256), dim3(512), args, 0, stream);

    hipLaunchKernelGGL(k3_p1, dim3(4096), dim3(256), 0, stream, pw1r, pb1r, ws);
    hipLaunchKernelGGL(k3_p2, dim3(4096), dim3(256), 0, stream, pgr, pber, pw2r, pb2r, ws, out);
    hipLaunchKernelGGL(k4_out, dim3(2112), dim3(256), 0, stream, ws, out);
}

// Round 5
// 7878.371 us; speedup vs baseline: 3.0422x; 1.2801x over previous
//
#include <hip/hip_runtime.h>

#define NB 64      // batch
#define NT 64      // time
#define ND 1024    // DETER
#define NH 1024    // HID
#define NE 1536    // EMBED
#define NA 6       // ACT
#define NSC 1024   // STOCH*CLASSES
#define GIN 1030   // GRU_IN
#define W1STR 2560 // post_w1 row stride (ND+NE)
#define EPS 1e-5f

// ---- workspace layout (float offsets) ----
#define O_EPRE   0u            // [T][NH][NB]  epre, then phT[t] in-place, then k3 ph1
#define O_HHIST  4194304u      // [T][ND][NB]
#define O_LHIST  8388608u      // [T][NSC][NB] (post logits, [t][j][b])
#define O_EMBT   4194304u      // overlay on HHIST+LHIST pre-scan: [T][NE][NB]
#define O_BAR    12582912u     // epoch counter (u32)
#define O_FLAGS  12582976u     // u32[256*32] per-block arrival flags (128B stride)
#define O_GMAX   12812288u     // u64[32][NB] packed argmax
#define O_ZIDX   12816384u     // int[T][32][NB]
#define O_ACTT   12947456u     // [T][NA][NB]
#define O_KEEPT  12972032u     // [T][NB]
#define O_PSTAT  12976128u     // [T][NB][2] prior LN stats (k3)
// end: 12984320 floats = ~49.5 MB

// out layout (floats)
#define OUT_LATENT 0u
#define OUT_HSEQ   8388608u
#define OUT_POST   12582912u
#define OUT_PRIOR  16777216u

// ---- coherence-point bypass ops (agent scope, relaxed) ----
__device__ __forceinline__ float gload(const float* p) {
    return __uint_as_float(__hip_atomic_load((const unsigned int*)p,
                __ATOMIC_RELAXED, __HIP_MEMORY_SCOPE_AGENT));
}
__device__ __forceinline__ void gstoref(float* p, float v) {
    __hip_atomic_store((unsigned int*)p, __float_as_uint(v),
                __ATOMIC_RELAXED, __HIP_MEMORY_SCOPE_AGENT);
}
__device__ __forceinline__ unsigned long long gload64(const unsigned long long* p) {
    return __hip_atomic_load(p, __ATOMIC_RELAXED, __HIP_MEMORY_SCOPE_AGENT);
}
__device__ __forceinline__ void gstore64(unsigned long long* p, unsigned long long v) {
    __hip_atomic_store(p, v, __ATOMIC_RELAXED, __HIP_MEMORY_SCOPE_AGENT);
}
__device__ __forceinline__ unsigned int gload32(const unsigned int* p) {
    return __hip_atomic_load(p, __ATOMIC_RELAXED, __HIP_MEMORY_SCOPE_AGENT);
}
__device__ __forceinline__ void gstore32(unsigned int* p, unsigned int v) {
    __hip_atomic_store(p, v, __ATOMIC_RELAXED, __HIP_MEMORY_SCOPE_AGENT);
}

// Flags+leader barrier: one bypass store per block (no same-line RMW pileup),
// block 0 sweeps the flag array, then publishes epoch. Relaxed -> L2 stays warm.
__device__ __forceinline__ void gbar2(unsigned int* flags, unsigned int* epoch,
                                      int blk, unsigned int ep, int* miss) {
    asm volatile("s_waitcnt vmcnt(0) lgkmcnt(0)" ::: "memory");
    __syncthreads();
    const int tid = threadIdx.x;
    if (blk == 0) {
        for (;;) {
            if (tid == 0) *miss = 0;
            __syncthreads();
            if (tid > 0 && tid < 256) {
                if (gload32(&flags[tid * 32]) < ep) atomicOr(miss, 1);
            }
            __syncthreads();
            if (!*miss) break;
            __builtin_amdgcn_s_sleep(1);
        }
        __syncthreads();
        if (tid == 0) gstore32(epoch, ep);
    } else {
        if (tid == 0) {
            gstore32(&flags[blk * 32], ep);
            while (gload32(epoch) < ep) __builtin_amdgcn_s_sleep(2);
        }
    }
    __syncthreads();
}

// =================== K0: transposes + zero-init ===================
__global__ void k0_prep(const float* __restrict__ embeds,
                        const float* __restrict__ actions,
                        const int* __restrict__ isfirst,
                        float* __restrict__ ws)
{
    int blk = blockIdx.x, tid = threadIdx.x;
    int rr = tid >> 6, ln = tid & 63;
    if (blk < 1536) {
        // embeds (B,T,E) -> emb_T [t][e][b]
        int t = blk / 24, et = blk % 24, e0 = et * 64;
        __shared__ float tile[64][65];
        for (int q = 0; q < 16; ++q) {
            int b = q * 4 + rr;
            tile[b][ln] = embeds[((size_t)b * NT + t) * NE + e0 + ln];
        }
        __syncthreads();
        float* embT = ws + O_EMBT + (size_t)t * NE * NB;
        for (int q = 0; q < 16; ++q) {
            int e = q * 4 + rr;
            embT[(size_t)(e0 + e) * NB + ln] = tile[ln][e];
        }
    } else if (blk == 1536) {
        for (int i = tid; i < NT * NA * NB; i += 256) {
            int t = i / (NA * NB); int rem = i % (NA * NB);
            int a = rem / NB; int b = rem % NB;
            ws[O_ACTT + i] = actions[((size_t)b * NT + t) * NA + a];
        }
        for (int i = tid; i < NT * NB; i += 256) {
            int t = i / NB, b = i % NB;
            ws[O_KEEPT + i] = 1.f - (float)isfirst[(size_t)b * NT + t];
        }
    } else {
        if (tid == 0) *(unsigned int*)(ws + O_BAR) = 0u;
        for (int i = tid; i < 256 * 32; i += 256)
            ((unsigned int*)(ws + O_FLAGS))[i] = 0u;
        for (int i = tid; i < NT * NB * 2; i += 256)
            ws[O_PSTAT + i] = 0.f;
    }
}

// =================== K1: E_pre = emb @ post_w1[:,1024:]^T ===================
__global__ __launch_bounds__(256) void k1_epre(const float* __restrict__ qw1,
                                               float* __restrict__ ws)
{
    int blk = blockIdx.x;
    int t = blk >> 6, kg = blk & 63, k0 = kg * 16;
    int tid = threadIdx.x, w = tid >> 6, lane = tid & 63;
    const float* embT = ws + O_EMBT + (size_t)t * NE * NB;
    float acc[16];
#pragma unroll
    for (int i = 0; i < 16; ++i) acc[i] = 0.f;
    int e0 = w * 384;
    for (int e = e0; e < e0 + 384; ++e) {
        float ev = embT[(size_t)e * NB + lane];
#pragma unroll
        for (int kk = 0; kk < 16; ++kk)
            acc[kk] = fmaf(qw1[(size_t)(k0 + kk) * W1STR + ND + e], ev, acc[kk]);
    }
    __shared__ float red[4][16][64];
#pragma unroll
    for (int kk = 0; kk < 16; ++kk) red[w][kk][lane] = acc[kk];
    __syncthreads();
    float* epre = ws + O_EPRE + (size_t)t * NH * NB;
    for (int q = 0; q < 4; ++q) {
        int slot = tid + q * 256;
        int kk = slot >> 6, b = slot & 63;
        float v = red[0][kk][b] + red[1][kk][b] + red[2][kk][b] + red[3][kk][b];
        epre[(size_t)(k0 + kk) * NB + b] = v;
    }
}

// =================== K2: the scan ===================
// 256 blocks x 512 threads. Whh slice LDS-resident (48KB) -> frees L2 so
// Wih/qw1/qw2 slices stay L2-resident (per-XCD ~2MB < 4MB). Flags barrier.
__global__ __launch_bounds__(512, 2)
void k2_scan(const float* __restrict__ Wih, const float* __restrict__ Whh,
             const float* __restrict__ bih, const float* __restrict__ bhh,
             const float* __restrict__ qw1, const float* __restrict__ qb1,
             const float* __restrict__ qg,  const float* __restrict__ qbe,
             const float* __restrict__ qw2, const float* __restrict__ qb2,
             float* __restrict__ ws)
{
    const int blk = blockIdx.x, tid = threadIdx.x;
    const int w = tid >> 6, lane = tid & 63;
    const int d0 = blk * 4;                        // owned 4 dims
    const int dd = (tid >> 6) & 3, bb = tid & 63;  // finalize mapping (tid<256)

    float* hhist = ws + O_HHIST;
    float* lhist = ws + O_LHIST;
    float* epre  = ws + O_EPRE;          // also phT[t] in-place
    unsigned int* epoch = (unsigned int*)(ws + O_BAR);
    unsigned int* flags = (unsigned int*)(ws + O_FLAGS);
    unsigned long long* gmax = (unsigned long long*)(ws + O_GMAX);
    int* zidx = (int*)(ws + O_ZIDX);
    const float* actT  = ws + O_ACTT;
    const float* keepT = ws + O_KEEPT;

    __shared__ __align__(16) float sWhh[12][1024];   // 48KB: rows gate*4+dd
    __shared__ float sRed[8][4][64];                  // 8KB
    __shared__ float smean[64], srstd[64];
    __shared__ unsigned long long pkst[4][64];        // 2KB
    __shared__ int sMiss;

    // ---- stage Whh slice once (coalesced float4 per row) ----
    for (int i4 = tid; i4 < 12 * 256; i4 += 512) {
        int r = i4 >> 8, k4 = (i4 & 255) * 4;
        int row = (r >> 2) * 1024 + d0 + (r & 3);
        *(float4*)&sWhh[r][k4] = *(const float4*)&Whh[(size_t)row * ND + k4];
    }
    __syncthreads();

    unsigned int ep = 0;

    for (int t = 0; t < NT; ++t) {
        // ---------------- PHASE A: GRU -> h_new ----------------
        {
            float acc[12];
#pragma unroll
            for (int r = 0; r < 12; ++r) acc[r] = 0.f;
            if (t > 0) {
                const float* hp = hhist + (size_t)(t - 1) * ND * NB;  // normal reads
                int base = w * 128;
                for (int kt = 0; kt < 128; kt += 16) {
                    float hbuf[16];
#pragma unroll
                    for (int j = 0; j < 16; ++j)
                        hbuf[j] = hp[(size_t)(base + kt + j) * NB + lane];
#pragma unroll
                    for (int j4 = 0; j4 < 16; j4 += 4) {
                        int k = base + kt + j4;
#pragma unroll
                        for (int r = 0; r < 12; ++r) {
                            float4 wv = *(const float4*)&sWhh[r][k];   // LDS broadcast
                            acc[r] = fmaf(wv.x, hbuf[j4 + 0], acc[r]);
                            acc[r] = fmaf(wv.y, hbuf[j4 + 1], acc[r]);
                            acc[r] = fmaf(wv.z, hbuf[j4 + 2], acc[r]);
                            acc[r] = fmaf(wv.w, hbuf[j4 + 3], acc[r]);
                        }
                    }
                }
            }
            float gh[3] = {0.f, 0.f, 0.f};
#pragma unroll
            for (int g2 = 0; g2 < 3; ++g2) {
                __syncthreads();
#pragma unroll
                for (int q = 0; q < 4; ++q) sRed[w][q][lane] = acc[g2 * 4 + q];
                __syncthreads();
                if (tid < 256) {
                    float s = 0.f;
#pragma unroll
                    for (int ww = 0; ww < 8; ++ww) s += sRed[ww][dd][bb];
                    gh[g2] = s;
                }
            }
            if (tid < 256) {
                int d = d0 + dd;
                float keep = keepT[t * NB + bb];
                float ghr = fmaf(keep, gh[0], bhh[d]);
                float ghz = fmaf(keep, gh[1], bhh[1024 + d]);
                float ghn = fmaf(keep, gh[2], bhh[2048 + d]);
                float gxr = bih[d], gxz = bih[1024 + d], gxn = bih[2048 + d];
                if (t > 0) {
                    unsigned long long pkbuf[32];
#pragma unroll 8
                    for (int g = 0; g < 32; ++g)
                        pkbuf[g] = gload64(&gmax[g * 64 + bb]);
                    float sr = 0.f, sz = 0.f, sn = 0.f;
#pragma unroll 8
                    for (int g = 0; g < 32; ++g) {
                        int c = 31 - (int)((unsigned)pkbuf[g] & 31u);
                        int col = g * 32 + c;
                        sr += Wih[(size_t)d * GIN + col];
                        sz += Wih[(size_t)(1024 + d) * GIN + col];
                        sn += Wih[(size_t)(2048 + d) * GIN + col];
                        if (blk == 0 && dd == 0) zidx[(t - 1) * 32 * NB + g * NB + bb] = c;
                    }
                    gxr = fmaf(keep, sr, gxr);
                    gxz = fmaf(keep, sz, gxz);
                    gxn = fmaf(keep, sn, gxn);
                }
#pragma unroll
                for (int a = 0; a < NA; ++a) {
                    float av = actT[(t * NA + a) * NB + bb];
                    gxr = fmaf(Wih[(size_t)d * GIN + ND + a], av, gxr);
                    gxz = fmaf(Wih[(size_t)(1024 + d) * GIN + ND + a], av, gxz);
                    gxn = fmaf(Wih[(size_t)(2048 + d) * GIN + ND + a], av, gxn);
                }
                float r = 1.f / (1.f + __expf(-(gxr + ghr)));
                float u = 1.f / (1.f + __expf(-(gxz + ghz)));
                float n = tanhf(gxn + r * ghn);
                float hprevm = 0.f;
                if (t > 0)
                    hprevm = keep * hhist[((size_t)(t - 1) * ND + d) * NB + bb];  // L2-warm
                float hnew = (1.f - u) * n + u * hprevm;
                gstoref(&hhist[((size_t)t * ND + d) * NB + bb], hnew);  // bypass -> L3
            }
        }
        ++ep; gbar2(flags, epoch, blk, ep, &sMiss);   // S1
        // -------- PHASE B: post w1 (h part) + E_pre -> phT (in epre[t]) --------
        {
            const float* hrow = hhist + (size_t)t * ND * NB;   // normal (first touch fresh)
            float acc4[4] = {0.f, 0.f, 0.f, 0.f};
            int base = w * 128;
            for (int kt = 0; kt < 128; kt += 16) {
                float hbuf[16];
#pragma unroll
                for (int j = 0; j < 16; ++j)
                    hbuf[j] = hrow[(size_t)(base + kt + j) * NB + lane];
#pragma unroll
                for (int j = 0; j < 16; ++j) {
                    int k = base + kt + j;
#pragma unroll
                    for (int rr = 0; rr < 4; ++rr)
                        acc4[rr] = fmaf(qw1[(size_t)(d0 + rr) * W1STR + k], hbuf[j], acc4[rr]);
                }
            }
            __syncthreads();
#pragma unroll
            for (int rr = 0; rr < 4; ++rr) sRed[w][rr][lane] = acc4[rr];
            if (blk == 0 && tid >= 256) {   // reset argmax accumulators (waves 4-7)
                for (int i = tid - 256; i < 2048; i += 256) gstore64(&gmax[i], 0ull);
            }
            __syncthreads();
            if (tid < 256) {
                float s = 0.f;
#pragma unroll
                for (int ww = 0; ww < 8; ++ww) s += sRed[ww][dd][bb];
                size_t idx = ((size_t)t * NH + d0 + dd) * NB + bb;
                float v = s + qb1[d0 + dd] + gload(&epre[idx]);   // bypass read
                gstoref(&epre[idx], v);                           // bypass write -> L3
            }
        }
        ++ep; gbar2(flags, epoch, blk, ep, &sMiss);   // S2
        // ---------------- PHASE C: LN+SiLU+post w2 + argmax ----------------
        {
            const float* phTn = epre + (size_t)t * NH * NB;    // NORMAL reads (fresh lines)
            int base = w * 128;
            // pass 1: LN stats
            float s1 = 0.f, s2 = 0.f;
            for (int kt = 0; kt < 128; kt += 16) {
                float hbuf[16];
#pragma unroll
                for (int j = 0; j < 16; ++j)
                    hbuf[j] = phTn[(size_t)(base + kt + j) * NB + lane];
#pragma unroll
                for (int j = 0; j < 16; ++j) { s1 += hbuf[j]; s2 = fmaf(hbuf[j], hbuf[j], s2); }
            }
            __syncthreads();
            sRed[w][0][lane] = s1; sRed[w][1][lane] = s2;
            __syncthreads();
            if (tid < 64) {
                float a = 0.f, q = 0.f;
#pragma unroll
                for (int ww = 0; ww < 8; ++ww) { a += sRed[ww][0][tid]; q += sRed[ww][1][tid]; }
                float mean = a * (1.f / NH);
                float var = q * (1.f / NH) - mean * mean;
                smean[tid] = mean;
                srstd[tid] = 1.f / sqrtf(var + EPS);
            }
            __syncthreads();
            float mean = smean[lane], rstd = srstd[lane];
            float acc4[4] = {0.f, 0.f, 0.f, 0.f};
            for (int kt = 0; kt < 128; kt += 16) {
                float hbuf[16];
#pragma unroll
                for (int j = 0; j < 16; ++j)
                    hbuf[j] = phTn[(size_t)(base + kt + j) * NB + lane];   // L2-hot re-read
#pragma unroll
                for (int j = 0; j < 16; ++j) {
                    int k = base + kt + j;
                    float x = fmaf((hbuf[j] - mean) * rstd, qg[k], qbe[k]);
                    float sl = x / (1.f + __expf(-x));
#pragma unroll
                    for (int jj = 0; jj < 4; ++jj)
                        acc4[jj] = fmaf(qw2[(size_t)(d0 + jj) * NH + k], sl, acc4[jj]);
                }
            }
            __syncthreads();
#pragma unroll
            for (int jj = 0; jj < 4; ++jj) sRed[w][jj][lane] = acc4[jj];
            __syncthreads();
            if (tid < 256) {
                float s = 0.f;
#pragma unroll
                for (int ww = 0; ww < 8; ++ww) s += sRed[ww][dd][bb];
                float lg = s + qb2[d0 + dd];
                lhist[((size_t)t * NSC + d0 + dd) * NB + bb] = lg;   // normal store
                unsigned bits = __float_as_uint(lg);
                unsigned key = (bits & 0x80000000u) ? ~bits : (bits | 0x80000000u);
                int cls = (d0 + dd) & 31;
                pkst[dd][bb] = ((unsigned long long)key << 32) | (unsigned long long)(31 - cls);
            }
            __syncthreads();
            if (tid < 64) {
                unsigned long long m = pkst[0][tid];
                if (pkst[1][tid] > m) m = pkst[1][tid];
                if (pkst[2][tid] > m) m = pkst[2][tid];
                if (pkst[3][tid] > m) m = pkst[3][tid];
                __hip_atomic_fetch_max(&gmax[(d0 >> 5) * 64 + tid], m,
                                       __ATOMIC_RELAXED, __HIP_MEMORY_SCOPE_AGENT);
            }
        }
        ++ep; gbar2(flags, epoch, blk, ep, &sMiss);   // S3
    }
    if (blk == 0 && tid < 64) {
        for (int g = 0; g < 32; ++g) {
            unsigned long long pk = gload64(&gmax[g * 64 + tid]);
            zidx[(NT - 1) * 32 * NB + g * NB + tid] = 31 - (int)((unsigned)pk & 31u);
        }
    }
}

// =================== K3a: prior w1 + LN stats ===================
__global__ __launch_bounds__(256) void k3_p1(const float* __restrict__ w1p,
                                             const float* __restrict__ b1p,
                                             float* __restrict__ ws)
{
    int blk = blockIdx.x;
    int t = blk >> 6, kg = blk & 63, k0 = kg * 16;
    int tid = threadIdx.x, w = tid >> 6, lane = tid & 63;
    const float* hrow = ws + O_HHIST + (size_t)t * ND * NB;
    float acc[16];
#pragma unroll
    for (int i = 0; i < 16; ++i) acc[i] = 0.f;
    int dd0 = w * 256;
    for (int d = dd0; d < dd0 + 256; ++d) {
        float hv = hrow[(size_t)d * NB + lane];
#pragma unroll
        for (int kk = 0; kk < 16; ++kk)
            acc[kk] = fmaf(w1p[(size_t)(k0 + kk) * ND + d], hv, acc[kk]);
    }
    __shared__ float red[4][16][64];
    __shared__ float vst[16][64];
#pragma unroll
    for (int kk = 0; kk < 16; ++kk) red[w][kk][lane] = acc[kk];
    __syncthreads();
    float* ph1 = ws + O_EPRE + (size_t)t * NH * NB;  // reuse E_pre region
    for (int q = 0; q < 4; ++q) {
        int slot = tid + q * 256;
        int kk = slot >> 6, b = slot & 63;
        float v = red[0][kk][b] + red[1][kk][b] + red[2][kk][b] + red[3][kk][b] + b1p[k0 + kk];
        ph1[(size_t)(k0 + kk) * NB + b] = v;
        vst[kk][b] = v;
    }
    __syncthreads();
    if (tid < 64) {
        float s1 = 0.f, s2 = 0.f;
#pragma unroll
        for (int kk = 0; kk < 16; ++kk) { float v = vst[kk][tid]; s1 += v; s2 = fmaf(v, v, s2); }
        float* pst = ws + O_PSTAT;
        atomicAdd(&pst[(t * NB + tid) * 2 + 0], s1);
        atomicAdd(&pst[(t * NB + tid) * 2 + 1], s2);
    }
}

// =================== K3b: prior LN+SiLU+w2 -> prior_logits ===================
__global__ __launch_bounds__(256) void k3_p2(const float* __restrict__ gp,
                                             const float* __restrict__ bep,
                                             const float* __restrict__ w2p,
                                             const float* __restrict__ b2p,
                                             float* __restrict__ ws,
                                             float* __restrict__ out)
{
    int blk = blockIdx.x;
    int t = blk >> 6, jg = blk & 63, j0 = jg * 16;
    int tid = threadIdx.x, w = tid >> 6, lane = tid & 63;
    const float* ph1 = ws + O_EPRE + (size_t)t * NH * NB;
    const float* pst = ws + O_PSTAT;
    __shared__ float smean[64], srstd[64];
    if (tid < 64) {
        float s1 = pst[(t * NB + tid) * 2], s2 = pst[(t * NB + tid) * 2 + 1];
        float mean = s1 * (1.f / NH);
        float var = s2 * (1.f / NH) - mean * mean;
        smean[tid] = mean;
        srstd[tid] = 1.f / sqrtf(var + EPS);
    }
    __syncthreads();
    float mean = smean[lane], rstd = srstd[lane];
    float acc[16];
#pragma unroll
    for (int i = 0; i < 16; ++i) acc[i] = 0.f;
    int kk0 = w * 256;
    for (int k = kk0; k < kk0 + 256; ++k) {
        float v = ph1[(size_t)k * NB + lane];
        float x = fmaf((v - mean) * rstd, gp[k], bep[k]);
        float s = x / (1.f + __expf(-x));
#pragma unroll
        for (int jj = 0; jj < 16; ++jj)
            acc[jj] = fmaf(w2p[(size_t)(j0 + jj) * NH + k], s, acc[jj]);
    }
    __shared__ float red[4][16][64];
#pragma unroll
    for (int jj = 0; jj < 16; ++jj) red[w][jj][lane] = acc[jj];
    __syncthreads();
    float* prior = out + OUT_PRIOR;
    for (int q = 0; q < 4; ++q) {
        int slot = tid + q * 256;
        int b = slot >> 4, jj = slot & 15;
        float v = red[0][jj][b] + red[1][jj][b] + red[2][jj][b] + red[3][jj][b] + b2p[j0 + jj];
        prior[((size_t)b * NT + t) * NSC + j0 + jj] = v;
    }
}

// =================== K4: write-out transposes ===================
__global__ void k4_out(float* __restrict__ ws, float* __restrict__ out)
{
    int blk = blockIdx.x, tid = threadIdx.x;
    int rr = tid >> 6, ln = tid & 63;
    float* latent = out + OUT_LATENT;
    float* hseq = out + OUT_HSEQ;
    float* post = out + OUT_POST;
    if (blk < 1024) {
        int t = blk >> 4, dt = blk & 15, base_d = dt * 64;
        __shared__ float tile[64][65];
        const float* hh = ws + O_HHIST + (size_t)t * ND * NB;
        for (int q = 0; q < 16; ++q) {
            int row = q * 4 + rr;
            tile[row][ln] = hh[(size_t)(base_d + row) * NB + ln];
        }
        __syncthreads();
        for (int q = 0; q < 16; ++q) {
            int b = q * 4 + rr;
            float v = tile[ln][b];
            hseq[((size_t)b * NT + t) * ND + base_d + ln] = v;
            latent[((size_t)b * NT + t) * 2048 + base_d + ln] = v;
        }
    } else if (blk < 2048) {
        int bb = blk - 1024;
        int t = bb >> 4, jt = bb & 15, base_j = jt * 64;
        __shared__ float tile[64][65];
        const float* lh = ws + O_LHIST + (size_t)t * NSC * NB;
        for (int q = 0; q < 16; ++q) {
            int row = q * 4 + rr;
            tile[row][ln] = lh[(size_t)(base_j + row) * NB + ln];
        }
        __syncthreads();
        for (int q = 0; q < 16; ++q) {
            int b = q * 4 + rr;
            post[((size_t)b * NT + t) * NSC + base_j + ln] = tile[ln][b];
        }
    } else {
        int t = blk - 2048;
        const int* zi = (const int*)(ws + O_ZIDX) + t * 32 * NB;
        __shared__ int zl[32];
        for (int b = 0; b < NB; ++b) {
            if (tid < 32) zl[tid] = zi[tid * NB + b];
            __syncthreads();
            for (int q = 0; q < 4; ++q) {
                int j = q * 256 + tid;
                latent[((size_t)b * NT + t) * 2048 + 1024 + j] = (zl[j >> 5] == (j & 31)) ? 1.f : 0.f;
            }
            __syncthreads();
        }
    }
}

extern "C" void kernel_launch(void* const* d_in, const int* in_sizes, int n_in,
                              void* d_out, int out_size, void* d_ws, size_t ws_size,
                              hipStream_t stream)
{
    const float* embeds  = (const float*)d_in[0];
    const float* actions = (const float*)d_in[1];
    const int*   isfirst = (const int*)d_in[2];
    const float* Wih = (const float*)d_in[3];
    const float* Whh = (const float*)d_in[4];
    const float* bih = (const float*)d_in[5];
    const float* bhh = (const float*)d_in[6];
    const float* pw1r = (const float*)d_in[7];
    const float* pb1r = (const float*)d_in[8];
    const float* pgr  = (const float*)d_in[9];
    const float* pber = (const float*)d_in[10];
    const float* pw2r = (const float*)d_in[11];
    const float* pb2r = (const float*)d_in[12];
    const float* qw1 = (const float*)d_in[13];
    const float* qb1 = (const float*)d_in[14];
    const float* qg  = (const float*)d_in[15];
    const float* qbe = (const float*)d_in[16];
    const float* qw2 = (const float*)d_in[17];
    const float* qb2 = (const float*)d_in[18];
    float* out = (float*)d_out;
    float* ws = (float*)d_ws;

    hipLaunchKernelGGL(k0_prep, dim3(1538), dim3(256), 0, stream, embeds, actions, isfirst, ws);
    hipLaunchKernelGGL(k1_epre, dim3(4096), dim3(256), 0, stream, qw1, ws);

    void* args[] = {(void*)&Wih, (void*)&Whh, (void*)&bih, (void*)&bhh,
                    (void*)&qw1, (void*)&qb1, (void*)&qg, (void*)&qbe,
                    (void*)&qw2, (void*)&qb2, (void*)&ws};
    hipLaunchCooperativeKernel((void*)k2_scan, dim3(256), dim3(512), args, 0, stream);

    hipLaunchKernelGGL(k3_p1, dim3(4096), dim3(256), 0, stream, pw1r, pb1r, ws);
    hipLaunchKernelGGL(k3_p2, dim3(4096), dim3(256), 0, stream, pgr, pber, pw2r, pb2r, ws, out);
    hipLaunchKernelGGL(k4_out, dim3(2112), dim3(256), 0, stream, ws, out);
}

// Round 6
// 7406.211 us; speedup vs baseline: 3.2362x; 1.0638x over previous
//
#include <hip/hip_runtime.h>

#define NB 64      // batch
#define NT 64      // time
#define ND 1024    // DETER
#define NH 1024    // HID
#define NE 1536    // EMBED
#define NA 6       // ACT
#define NSC 1024   // STOCH*CLASSES
#define GIN 1030   // GRU_IN
#define W1STR 2560 // post_w1 row stride (ND+NE)
#define EPS 1e-5f

typedef float f4v __attribute__((ext_vector_type(4)));

// ---- workspace layout (float offsets) ----
#define O_EPRE   0u            // [T][NH][NB]  epre, then phT[t] in-place, then k3 ph1
#define O_HHIST  4194304u      // [T][ND][NB]
#define O_LHIST  8388608u      // [T][NSC][NB] (post logits, [t][j][b])
#define O_EMBT   4194304u      // overlay on HHIST+LHIST pre-scan: [T][NE][NB]
#define O_BAR    12582912u     // epoch counter (u32)
#define O_FLAGS  12582976u     // u32[256*32] per-block arrival flags (128B stride)
#define O_ZC     12713984u     // u32[8][64] packed 5-bit argmax indices (4 groups/u32)
#define O_GMAX   12812288u     // u64[32][NB] packed argmax keys
#define O_ZIDX   12816384u     // int[T][32][NB]
#define O_ACTT   12947456u     // [T][NA][NB]
#define O_KEEPT  12972032u     // [T][NB]
#define O_PSTAT  12976128u     // [T][NB][2] prior LN stats (k3)
// end: 12984320 floats = ~49.5 MB

// out layout (floats)
#define OUT_LATENT 0u
#define OUT_HSEQ   8388608u
#define OUT_POST   12582912u
#define OUT_PRIOR  16777216u

// ---- coherence-point bypass ops (agent scope, relaxed) ----
__device__ __forceinline__ float gload(const float* p) {
    return __uint_as_float(__hip_atomic_load((const unsigned int*)p,
                __ATOMIC_RELAXED, __HIP_MEMORY_SCOPE_AGENT));
}
__device__ __forceinline__ unsigned long long gload64(const unsigned long long* p) {
    return __hip_atomic_load(p, __ATOMIC_RELAXED, __HIP_MEMORY_SCOPE_AGENT);
}
__device__ __forceinline__ void gstore64(unsigned long long* p, unsigned long long v) {
    __hip_atomic_store(p, v, __ATOMIC_RELAXED, __HIP_MEMORY_SCOPE_AGENT);
}
__device__ __forceinline__ unsigned int gload32(const unsigned int* p) {
    return __hip_atomic_load(p, __ATOMIC_RELAXED, __HIP_MEMORY_SCOPE_AGENT);
}
__device__ __forceinline__ void gstore32(unsigned int* p, unsigned int v) {
    __hip_atomic_store(p, v, __ATOMIC_RELAXED, __HIP_MEMORY_SCOPE_AGENT);
}
// 16B L2-bypass store (device-coherent): lands at L3, visible to all XCDs
// after vmcnt(0)+flag release. Safe only for lines with no valid L2 copies
// anywhere (t-indexed, first touch) — holds for hhist[t]/epre[t] writes.
__device__ __forceinline__ void gstore128(float* p, f4v v) {
    asm volatile("global_store_dwordx4 %0, %1, off sc0 sc1"
                 :: "v"(p), "v"(v) : "memory");
}

// =================== K0: transposes + zero-init ===================
__global__ void k0_prep(const float* __restrict__ embeds,
                        const float* __restrict__ actions,
                        const int* __restrict__ isfirst,
                        float* __restrict__ ws)
{
    int blk = blockIdx.x, tid = threadIdx.x;
    int rr = tid >> 6, ln = tid & 63;
    if (blk < 1536) {
        // embeds (B,T,E) -> emb_T [t][e][b]
        int t = blk / 24, et = blk % 24, e0 = et * 64;
        __shared__ float tile[64][65];
        for (int q = 0; q < 16; ++q) {
            int b = q * 4 + rr;
            tile[b][ln] = embeds[((size_t)b * NT + t) * NE + e0 + ln];
        }
        __syncthreads();
        float* embT = ws + O_EMBT + (size_t)t * NE * NB;
        for (int q = 0; q < 16; ++q) {
            int e = q * 4 + rr;
            embT[(size_t)(e0 + e) * NB + ln] = tile[ln][e];
        }
    } else if (blk == 1536) {
        for (int i = tid; i < NT * NA * NB; i += 256) {
            int t = i / (NA * NB); int rem = i % (NA * NB);
            int a = rem / NB; int b = rem % NB;
            ws[O_ACTT + i] = actions[((size_t)b * NT + t) * NA + a];
        }
        for (int i = tid; i < NT * NB; i += 256) {
            int t = i / NB, b = i % NB;
            ws[O_KEEPT + i] = 1.f - (float)isfirst[(size_t)b * NT + t];
        }
    } else {
        if (tid == 0) *(unsigned int*)(ws + O_BAR) = 0u;
        for (int i = tid; i < 256 * 32; i += 256)
            ((unsigned int*)(ws + O_FLAGS))[i] = 0u;
        for (int i = tid; i < NT * NB * 2; i += 256)
            ws[O_PSTAT + i] = 0.f;
    }
}

// =================== K1: E_pre = emb @ post_w1[:,1024:]^T ===================
__global__ __launch_bounds__(256) void k1_epre(const float* __restrict__ qw1,
                                               float* __restrict__ ws)
{
    int blk = blockIdx.x;
    int t = blk >> 6, kg = blk & 63, k0 = kg * 16;
    int tid = threadIdx.x, w = tid >> 6, lane = tid & 63;
    const float* embT = ws + O_EMBT + (size_t)t * NE * NB;
    float acc[16];
#pragma unroll
    for (int i = 0; i < 16; ++i) acc[i] = 0.f;
    int e0 = w * 384;
    for (int e = e0; e < e0 + 384; ++e) {
        float ev = embT[(size_t)e * NB + lane];
#pragma unroll
        for (int kk = 0; kk < 16; ++kk)
            acc[kk] = fmaf(qw1[(size_t)(k0 + kk) * W1STR + ND + e], ev, acc[kk]);
    }
    __shared__ float red[4][16][64];
#pragma unroll
    for (int kk = 0; kk < 16; ++kk) red[w][kk][lane] = acc[kk];
    __syncthreads();
    float* epre = ws + O_EPRE + (size_t)t * NH * NB;
    for (int q = 0; q < 4; ++q) {
        int slot = tid + q * 256;
        int kk = slot >> 6, b = slot & 63;
        float v = red[0][kk][b] + red[1][kk][b] + red[2][kk][b] + red[3][kk][b];
        epre[(size_t)(k0 + kk) * NB + b] = v;
    }
}

// =================== K2: the scan ===================
// 256 blocks x 512 threads. Whh in LDS; Wih/qw1/qw2 L2-resident; flags
// barrier (relaxed). S3 barrier additionally compacts gmax (16KB keys) ->
// zc32 (2KB packed indices) inside block 0 before epoch publish.
__global__ __launch_bounds__(512, 2)
void k2_scan(const float* __restrict__ Wih, const float* __restrict__ Whh,
             const float* __restrict__ bih, const float* __restrict__ bhh,
             const float* __restrict__ qw1, const float* __restrict__ qb1,
             const float* __restrict__ qg,  const float* __restrict__ qbe,
             const float* __restrict__ qw2, const float* __restrict__ qb2,
             float* __restrict__ ws)
{
    const int blk = blockIdx.x, tid = threadIdx.x;
    const int w = tid >> 6, lane = tid & 63;
    const int d0 = blk * 4;                        // owned 4 dims
    const int dd = (tid >> 6) & 3, bb = tid & 63;  // finalize mapping (tid<256)

    float* hhist = ws + O_HHIST;
    float* lhist = ws + O_LHIST;
    float* epre  = ws + O_EPRE;          // also phT[t] in-place
    unsigned int* epoch = (unsigned int*)(ws + O_BAR);
    unsigned int* flags = (unsigned int*)(ws + O_FLAGS);
    unsigned int* zc32  = (unsigned int*)(ws + O_ZC);
    unsigned long long* gmax = (unsigned long long*)(ws + O_GMAX);
    int* zidx = (int*)(ws + O_ZIDX);
    const float* actT  = ws + O_ACTT;
    const float* keepT = ws + O_KEEPT;

    __shared__ __align__(16) float sWhh[12][1024];   // 48KB: rows gate*4+dd
    __shared__ float sRed[8][4][64];                  // 8KB
    __shared__ float sV[4][64];                       // 1KB staging for vec stores
    __shared__ float smean[64], srstd[64];
    __shared__ unsigned long long pkst[4][64];        // 2KB
    __shared__ int sMiss;

    // ---- stage Whh slice once (coalesced float4 per row) ----
    for (int i4 = tid; i4 < 12 * 256; i4 += 512) {
        int r = i4 >> 8, k4 = (i4 & 255) * 4;
        int row = (r >> 2) * 1024 + d0 + (r & 3);
        *(float4*)&sWhh[r][k4] = *(const float4*)&Whh[(size_t)row * ND + k4];
    }
    __syncthreads();

    unsigned int ep = 0;

    for (int t = 0; t < NT; ++t) {
        // ---------------- PHASE A: GRU -> h_new ----------------
        {
            float acc[12];
#pragma unroll
            for (int r = 0; r < 12; ++r) acc[r] = 0.f;
            if (t > 0) {
                const float* hp = hhist + (size_t)(t - 1) * ND * NB;  // L2-warm normal reads
                int base = w * 128;
                for (int kt = 0; kt < 128; kt += 16) {
                    float hbuf[16];
#pragma unroll
                    for (int j = 0; j < 16; ++j)
                        hbuf[j] = hp[(size_t)(base + kt + j) * NB + lane];
#pragma unroll
                    for (int j4 = 0; j4 < 16; j4 += 4) {
                        int k = base + kt + j4;
#pragma unroll
                        for (int r = 0; r < 12; ++r) {
                            float4 wv = *(const float4*)&sWhh[r][k];   // LDS broadcast
                            acc[r] = fmaf(wv.x, hbuf[j4 + 0], acc[r]);
                            acc[r] = fmaf(wv.y, hbuf[j4 + 1], acc[r]);
                            acc[r] = fmaf(wv.z, hbuf[j4 + 2], acc[r]);
                            acc[r] = fmaf(wv.w, hbuf[j4 + 3], acc[r]);
                        }
                    }
                }
            }
            float gh[3] = {0.f, 0.f, 0.f};
#pragma unroll
            for (int g2 = 0; g2 < 3; ++g2) {
                __syncthreads();
#pragma unroll
                for (int q = 0; q < 4; ++q) sRed[w][q][lane] = acc[g2 * 4 + q];
                __syncthreads();
                if (tid < 256) {
                    float s = 0.f;
#pragma unroll
                    for (int ww = 0; ww < 8; ++ww) s += sRed[ww][dd][bb];
                    gh[g2] = s;
                }
            }
            if (tid < 256) {
                int d = d0 + dd;
                float keep = keepT[t * NB + bb];
                float ghr = fmaf(keep, gh[0], bhh[d]);
                float ghz = fmaf(keep, gh[1], bhh[1024 + d]);
                float ghn = fmaf(keep, gh[2], bhh[2048 + d]);
                float gxr = bih[d], gxz = bih[1024 + d], gxn = bih[2048 + d];
                if (t > 0) {
                    unsigned int zcb[8];
#pragma unroll
                    for (int j = 0; j < 8; ++j)
                        zcb[j] = gload32(&zc32[j * 64 + bb]);   // 2KB packed indices
                    float sr = 0.f, sz = 0.f, sn = 0.f;
#pragma unroll 8
                    for (int g = 0; g < 32; ++g) {
                        int c = (int)((zcb[g >> 2] >> ((g & 3) * 8)) & 31u);
                        int col = g * 32 + c;
                        sr += Wih[(size_t)d * GIN + col];
                        sz += Wih[(size_t)(1024 + d) * GIN + col];
                        sn += Wih[(size_t)(2048 + d) * GIN + col];
                    }
                    gxr = fmaf(keep, sr, gxr);
                    gxz = fmaf(keep, sz, gxz);
                    gxn = fmaf(keep, sn, gxn);
                }
#pragma unroll
                for (int a = 0; a < NA; ++a) {
                    float av = actT[(t * NA + a) * NB + bb];
                    gxr = fmaf(Wih[(size_t)d * GIN + ND + a], av, gxr);
                    gxz = fmaf(Wih[(size_t)(1024 + d) * GIN + ND + a], av, gxz);
                    gxn = fmaf(Wih[(size_t)(2048 + d) * GIN + ND + a], av, gxn);
                }
                float r = 1.f / (1.f + __expf(-(gxr + ghr)));
                float u = 1.f / (1.f + __expf(-(gxz + ghz)));
                float n = tanhf(gxn + r * ghn);
                float hprevm = 0.f;
                if (t > 0)
                    hprevm = keep * hhist[((size_t)(t - 1) * ND + d) * NB + bb];  // L2-warm
                float hnew = (1.f - u) * n + u * hprevm;
                sV[dd][bb] = hnew;
            }
            __syncthreads();
            if (tid < 64) {   // vectorized bypass store: 4 rows x 16 float4
                int d2 = tid >> 4, bq = (tid & 15) * 4;
                f4v v = { sV[d2][bq], sV[d2][bq + 1], sV[d2][bq + 2], sV[d2][bq + 3] };
                gstore128(&hhist[((size_t)t * ND + d0 + d2) * NB + bq], v);
            }
        }
        // -------- S1 --------
        {
            ++ep;
            asm volatile("s_waitcnt vmcnt(0) lgkmcnt(0)" ::: "memory");
            __syncthreads();
            if (blk == 0) {
                for (;;) {
                    if (tid == 0) sMiss = 0;
                    __syncthreads();
                    if (tid > 0 && tid < 256)
                        if (gload32(&flags[tid * 32]) < ep) atomicOr(&sMiss, 1);
                    __syncthreads();
                    if (!sMiss) break;
                    __builtin_amdgcn_s_sleep(2);
                }
                __syncthreads();
                if (tid == 0) gstore32(epoch, ep);
            } else {
                if (tid == 0) {
                    gstore32(&flags[blk * 32], ep);
                    while (gload32(epoch) < ep) __builtin_amdgcn_s_sleep(16);
                }
            }
            __syncthreads();
        }
        // -------- PHASE B: post w1 (h part) + E_pre -> phT (in epre[t]) --------
        {
            const float* hrow = hhist + (size_t)t * ND * NB;   // normal (first touch fresh)
            float acc4[4] = {0.f, 0.f, 0.f, 0.f};
            int base = w * 128;
            for (int kt = 0; kt < 128; kt += 16) {
                float hbuf[16];
#pragma unroll
                for (int j = 0; j < 16; ++j)
                    hbuf[j] = hrow[(size_t)(base + kt + j) * NB + lane];
#pragma unroll
                for (int j = 0; j < 16; ++j) {
                    int k = base + kt + j;
#pragma unroll
                    for (int rr = 0; rr < 4; ++rr)
                        acc4[rr] = fmaf(qw1[(size_t)(d0 + rr) * W1STR + k], hbuf[j], acc4[rr]);
                }
            }
            __syncthreads();
#pragma unroll
            for (int rr = 0; rr < 4; ++rr) sRed[w][rr][lane] = acc4[rr];
            if (blk == 0 && tid >= 256) {   // reset argmax accumulators (waves 4-7)
                for (int i = tid - 256; i < 2048; i += 256) gstore64(&gmax[i], 0ull);
            }
            __syncthreads();
            if (tid < 256) {
                float s = 0.f;
#pragma unroll
                for (int ww = 0; ww < 8; ++ww) s += sRed[ww][dd][bb];
                size_t idx = ((size_t)t * NH + d0 + dd) * NB + bb;
                float v = s + qb1[d0 + dd] + gload(&epre[idx]);   // bypass read
                sV[dd][bb] = v;
            }
            __syncthreads();
            if (tid < 64) {
                int d2 = tid >> 4, bq = (tid & 15) * 4;
                f4v v = { sV[d2][bq], sV[d2][bq + 1], sV[d2][bq + 2], sV[d2][bq + 3] };
                gstore128(&epre[((size_t)t * NH + d0 + d2) * NB + bq], v);
            }
        }
        // -------- S2 --------
        {
            ++ep;
            asm volatile("s_waitcnt vmcnt(0) lgkmcnt(0)" ::: "memory");
            __syncthreads();
            if (blk == 0) {
                for (;;) {
                    if (tid == 0) sMiss = 0;
                    __syncthreads();
                    if (tid > 0 && tid < 256)
                        if (gload32(&flags[tid * 32]) < ep) atomicOr(&sMiss, 1);
                    __syncthreads();
                    if (!sMiss) break;
                    __builtin_amdgcn_s_sleep(2);
                }
                __syncthreads();
                if (tid == 0) gstore32(epoch, ep);
            } else {
                if (tid == 0) {
                    gstore32(&flags[blk * 32], ep);
                    while (gload32(epoch) < ep) __builtin_amdgcn_s_sleep(16);
                }
            }
            __syncthreads();
        }
        // ---------------- PHASE C: LN+SiLU+post w2 + argmax ----------------
        {
            const float* phTn = epre + (size_t)t * NH * NB;    // NORMAL reads (fresh lines)
            int base = w * 128;
            // pass 1: LN stats
            float s1 = 0.f, s2 = 0.f;
            for (int kt = 0; kt < 128; kt += 16) {
                float hbuf[16];
#pragma unroll
                for (int j = 0; j < 16; ++j)
                    hbuf[j] = phTn[(size_t)(base + kt + j) * NB + lane];
#pragma unroll
                for (int j = 0; j < 16; ++j) { s1 += hbuf[j]; s2 = fmaf(hbuf[j], hbuf[j], s2); }
            }
            __syncthreads();
            sRed[w][0][lane] = s1; sRed[w][1][lane] = s2;
            __syncthreads();
            if (tid < 64) {
                float a = 0.f, q = 0.f;
#pragma unroll
                for (int ww = 0; ww < 8; ++ww) { a += sRed[ww][0][tid]; q += sRed[ww][1][tid]; }
                float mean = a * (1.f / NH);
                float var = q * (1.f / NH) - mean * mean;
                smean[tid] = mean;
                srstd[tid] = 1.f / sqrtf(var + EPS);
            }
            __syncthreads();
            float mean = smean[lane], rstd = srstd[lane];
            float acc4[4] = {0.f, 0.f, 0.f, 0.f};
            for (int kt = 0; kt < 128; kt += 16) {
                float hbuf[16];
#pragma unroll
                for (int j = 0; j < 16; ++j)
                    hbuf[j] = phTn[(size_t)(base + kt + j) * NB + lane];   // L2-hot re-read
#pragma unroll
                for (int j = 0; j < 16; ++j) {
                    int k = base + kt + j;
                    float x = fmaf((hbuf[j] - mean) * rstd, qg[k], qbe[k]);
                    float sl = x / (1.f + __expf(-x));
#pragma unroll
                    for (int jj = 0; jj < 4; ++jj)
                        acc4[jj] = fmaf(qw2[(size_t)(d0 + jj) * NH + k], sl, acc4[jj]);
                }
            }
            __syncthreads();
#pragma unroll
            for (int jj = 0; jj < 4; ++jj) sRed[w][jj][lane] = acc4[jj];
            __syncthreads();
            if (tid < 256) {
                float s = 0.f;
#pragma unroll
                for (int ww = 0; ww < 8; ++ww) s += sRed[ww][dd][bb];
                float lg = s + qb2[d0 + dd];
                sV[dd][bb] = lg;
                unsigned bits = __float_as_uint(lg);
                unsigned key = (bits & 0x80000000u) ? ~bits : (bits | 0x80000000u);
                int cls = (d0 + dd) & 31;
                pkst[dd][bb] = ((unsigned long long)key << 32) | (unsigned long long)(31 - cls);
            }
            __syncthreads();
            if (tid < 64) {
                int d2 = tid >> 4, bq = (tid & 15) * 4;
                float4 v = { sV[d2][bq], sV[d2][bq + 1], sV[d2][bq + 2], sV[d2][bq + 3] };
                *(float4*)&lhist[((size_t)t * NSC + d0 + d2) * NB + bq] = v;  // normal store
                unsigned long long m = pkst[0][tid];
                if (pkst[1][tid] > m) m = pkst[1][tid];
                if (pkst[2][tid] > m) m = pkst[2][tid];
                if (pkst[3][tid] > m) m = pkst[3][tid];
                __hip_atomic_fetch_max(&gmax[(d0 >> 5) * 64 + tid], m,
                                       __ATOMIC_RELAXED, __HIP_MEMORY_SCOPE_AGENT);
            }
        }
        // -------- S3 (+ gmax -> zc32 compaction by block 0) --------
        {
            ++ep;
            asm volatile("s_waitcnt vmcnt(0) lgkmcnt(0)" ::: "memory");
            __syncthreads();
            if (blk == 0) {
                for (;;) {
                    if (tid == 0) sMiss = 0;
                    __syncthreads();
                    if (tid > 0 && tid < 256)
                        if (gload32(&flags[tid * 32]) < ep) atomicOr(&sMiss, 1);
                    __syncthreads();
                    if (!sMiss) break;
                    __builtin_amdgcn_s_sleep(2);
                }
                __syncthreads();
                if (tid < 64) {   // compact 16KB keys -> 2KB packed indices + zidx
                    unsigned int packed[8];
#pragma unroll
                    for (int j = 0; j < 8; ++j) packed[j] = 0u;
#pragma unroll 8
                    for (int g = 0; g < 32; ++g) {
                        unsigned long long pk = gload64(&gmax[g * 64 + tid]);
                        unsigned int c = 31u - ((unsigned int)pk & 31u);
                        packed[g >> 2] |= c << ((g & 3) * 8);
                        zidx[t * 32 * NB + g * NB + tid] = (int)c;   // normal store
                    }
#pragma unroll
                    for (int j = 0; j < 8; ++j)
                        gstore32(&zc32[j * 64 + tid], packed[j]);
                }
                asm volatile("s_waitcnt vmcnt(0)" ::: "memory");
                __syncthreads();
                if (tid == 0) gstore32(epoch, ep);
            } else {
                if (tid == 0) {
                    gstore32(&flags[blk * 32], ep);
                    while (gload32(epoch) < ep) __builtin_amdgcn_s_sleep(16);
                }
            }
            __syncthreads();
        }
    }
}

// =================== K3a: prior w1 + LN stats ===================
__global__ __launch_bounds__(256) void k3_p1(const float* __restrict__ w1p,
                                             const float* __restrict__ b1p,
                                             float* __restrict__ ws)
{
    int blk = blockIdx.x;
    int t = blk >> 6, kg = blk & 63, k0 = kg * 16;
    int tid = threadIdx.x, w = tid >> 6, lane = tid & 63;
    const float* hrow = ws + O_HHIST + (size_t)t * ND * NB;
    float acc[16];
#pragma unroll
    for (int i = 0; i < 16; ++i) acc[i] = 0.f;
    int dd0 = w * 256;
    for (int d = dd0; d < dd0 + 256; ++d) {
        float hv = hrow[(size_t)d * NB + lane];
#pragma unroll
        for (int kk = 0; kk < 16; ++kk)
            acc[kk] = fmaf(w1p[(size_t)(k0 + kk) * ND + d], hv, acc[kk]);
    }
    __shared__ float red[4][16][64];
    __shared__ float vst[16][64];
#pragma unroll
    for (int kk = 0; kk < 16; ++kk) red[w][kk][lane] = acc[kk];
    __syncthreads();
    float* ph1 = ws + O_EPRE + (size_t)t * NH * NB;  // reuse E_pre region
    for (int q = 0; q < 4; ++q) {
        int slot = tid + q * 256;
        int kk = slot >> 6, b = slot & 63;
        float v = red[0][kk][b] + red[1][kk][b] + red[2][kk][b] + red[3][kk][b] + b1p[k0 + kk];
        ph1[(size_t)(k0 + kk) * NB + b] = v;
        vst[kk][b] = v;
    }
    __syncthreads();
    if (tid < 64) {
        float s1 = 0.f, s2 = 0.f;
#pragma unroll
        for (int kk = 0; kk < 16; ++kk) { float v = vst[kk][tid]; s1 += v; s2 = fmaf(v, v, s2); }
        float* pst = ws + O_PSTAT;
        atomicAdd(&pst[(t * NB + tid) * 2 + 0], s1);
        atomicAdd(&pst[(t * NB + tid) * 2 + 1], s2);
    }
}

// =================== K3b: prior LN+SiLU+w2 -> prior_logits ===================
__global__ __launch_bounds__(256) void k3_p2(const float* __restrict__ gp,
                                             const float* __restrict__ bep,
                                             const float* __restrict__ w2p,
                                             const float* __restrict__ b2p,
                                             float* __restrict__ ws,
                                             float* __restrict__ out)
{
    int blk = blockIdx.x;
    int t = blk >> 6, jg = blk & 63, j0 = jg * 16;
    int tid = threadIdx.x, w = tid >> 6, lane = tid & 63;
    const float* ph1 = ws + O_EPRE + (size_t)t * NH * NB;
    const float* pst = ws + O_PSTAT;
    __shared__ float smean[64], srstd[64];
    if (tid < 64) {
        float s1 = pst[(t * NB + tid) * 2], s2 = pst[(t * NB + tid) * 2 + 1];
        float mean = s1 * (1.f / NH);
        float var = s2 * (1.f / NH) - mean * mean;
        smean[tid] = mean;
        srstd[tid] = 1.f / sqrtf(var + EPS);
    }
    __syncthreads();
    float mean = smean[lane], rstd = srstd[lane];
    float acc[16];
#pragma unroll
    for (int i = 0; i < 16; ++i) acc[i] = 0.f;
    int kk0 = w * 256;
    for (int k = kk0; k < kk0 + 256; ++k) {
        float v = ph1[(size_t)k * NB + lane];
        float x = fmaf((v - mean) * rstd, gp[k], bep[k]);
        float s = x / (1.f + __expf(-x));
#pragma unroll
        for (int jj = 0; jj < 16; ++jj)
            acc[jj] = fmaf(w2p[(size_t)(j0 + jj) * NH + k], s, acc[jj]);
    }
    __shared__ float red[4][16][64];
#pragma unroll
    for (int jj = 0; jj < 16; ++jj) red[w][jj][lane] = acc[jj];
    __syncthreads();
    float* prior = out + OUT_PRIOR;
    for (int q = 0; q < 4; ++q) {
        int slot = tid + q * 256;
        int b = slot >> 4, jj = slot & 15;
        float v = red[0][jj][b] + red[1][jj][b] + red[2][jj][b] + red[3][jj][b] + b2p[j0 + jj];
        prior[((size_t)b * NT + t) * NSC + j0 + jj] = v;
    }
}

// =================== K4: write-out transposes ===================
__global__ void k4_out(float* __restrict__ ws, float* __restrict__ out)
{
    int blk = blockIdx.x, tid = threadIdx.x;
    int rr = tid >> 6, ln = tid & 63;
    float* latent = out + OUT_LATENT;
    float* hseq = out + OUT_HSEQ;
    float* post = out + OUT_POST;
    if (blk < 1024) {
        int t = blk >> 4, dt = blk & 15, base_d = dt * 64;
        __shared__ float tile[64][65];
        const float* hh = ws + O_HHIST + (size_t)t * ND * NB;
        for (int q = 0; q < 16; ++q) {
            int row = q * 4 + rr;
            tile[row][ln] = hh[(size_t)(base_d + row) * NB + ln];
        }
        __syncthreads();
        for (int q = 0; q < 16; ++q) {
            int b = q * 4 + rr;
            float v = tile[ln][b];
            hseq[((size_t)b * NT + t) * ND + base_d + ln] = v;
            latent[((size_t)b * NT + t) * 2048 + base_d + ln] = v;
        }
    } else if (blk < 2048) {
        int bb = blk - 1024;
        int t = bb >> 4, jt = bb & 15, base_j = jt * 64;
        __shared__ float tile[64][65];
        const float* lh = ws + O_LHIST + (size_t)t * NSC * NB;
        for (int q = 0; q < 16; ++q) {
            int row = q * 4 + rr;
            tile[row][ln] = lh[(size_t)(base_j + row) * NB + ln];
        }
        __syncthreads();
        for (int q = 0; q < 16; ++q) {
            int b = q * 4 + rr;
            post[((size_t)b * NT + t) * NSC + base_j + ln] = tile[ln][b];
        }
    } else {
        int t = blk - 2048;
        const int* zi = (const int*)(ws + O_ZIDX) + t * 32 * NB;
        __shared__ int zl[32];
        for (int b = 0; b < NB; ++b) {
            if (tid < 32) zl[tid] = zi[tid * NB + b];
            __syncthreads();
            for (int q = 0; q < 4; ++q) {
                int j = q * 256 + tid;
                latent[((size_t)b * NT + t) * 2048 + 1024 + j] = (zl[j >> 5] == (j & 31)) ? 1.f : 0.f;
            }
            __syncthreads();
        }
    }
}

extern "C" void kernel_launch(void* const* d_in, const int* in_sizes, int n_in,
                              void* d_out, int out_size, void* d_ws, size_t ws_size,
                              hipStream_t stream)
{
    const float* embeds  = (const float*)d_in[0];
    const float* actions = (const float*)d_in[1];
    const int*   isfirst = (const int*)d_in[2];
    const float* Wih = (const float*)d_in[3];
    const float* Whh = (const float*)d_in[4];
    const float* bih = (const float*)d_in[5];
    const float* bhh = (const float*)d_in[6];
    const float* pw1r = (const float*)d_in[7];
    const float* pb1r = (const float*)d_in[8];
    const float* pgr  = (const float*)d_in[9];
    const float* pber = (const float*)d_in[10];
    const float* pw2r = (const float*)d_in[11];
    const float* pb2r = (const float*)d_in[12];
    const float* qw1 = (const float*)d_in[13];
    const float* qb1 = (const float*)d_in[14];
    const float* qg  = (const float*)d_in[15];
    const float* qbe = (const float*)d_in[16];
    const float* qw2 = (const float*)d_in[17];
    const float* qb2 = (const float*)d_in[18];
    float* out = (float*)d_out;
    float* ws = (float*)d_ws;

    hipLaunchKernelGGL(k0_prep, dim3(1538), dim3(256), 0, stream, embeds, actions, isfirst, ws);
    hipLaunchKernelGGL(k1_epre, dim3(4096), dim3(256), 0, stream, qw1, ws);

    void* args[] = {(void*)&Wih, (void*)&Whh, (void*)&bih, (void*)&bhh,
                    (void*)&qw1, (void*)&qb1, (void*)&qg, (void*)&qbe,
                    (void*)&qw2, (void*)&qb2, (void*)&ws};
    hipLaunchCooperativeKernel((void*)k2_scan, dim3(256), dim3(512), args, 0, stream);

    hipLaunchKernelGGL(k3_p1, dim3(4096), dim3(256), 0, stream, pw1r, pb1r, ws);
    hipLaunchKernelGGL(k3_p2, dim3(4096), dim3(256), 0, stream, pgr, pber, pw2r, pb2r, ws, out);
    hipLaunchKernelGGL(k4_out, dim3(2112), dim3(256), 0, stream, ws, out);
}